// Round 1
// baseline (758.599 us; speedup 1.0000x reference)
//
#include <hip/hip_runtime.h>
#include <hip/hip_bf16.h>
#include <stdint.h>

typedef unsigned short ushort_t;
typedef __attribute__((ext_vector_type(8))) short short8;
typedef __attribute__((ext_vector_type(4))) float f32x4;

#define L_SEQ   2048
#define BATCH   8
#define M_ROWS  16384          // BATCH*L_SEQ
#define DMODEL  1024
#define DINNER  2048
#define DSTATE  128
#define NHEADS  32
#define HEADDIM 64
#define CONVDIM 2304
#define DINPROJ 4384
#define EPSV    1e-5f

__device__ __forceinline__ float bf2f(ushort_t u){
  union { uint32_t i; float f; } v; v.i = ((uint32_t)u) << 16; return v.f;
}
__device__ __forceinline__ ushort_t f2bf(float f){
  union { float f; uint32_t i; } v; v.f = f;
  uint32_t r = v.i + 0x7fffu + ((v.i >> 16) & 1u);
  return (ushort_t)(r >> 16);
}

// ---------------- conversion / transpose kernels ----------------
__global__ void k_cvt_bf16(const float* __restrict__ src, ushort_t* __restrict__ dst, int n){
  int i = blockIdx.x * blockDim.x + threadIdx.x;
  if (i < n) dst[i] = f2bf(src[i]);
}
// w1t[j*64 + k] = w_proj[k*1024 + j]   (j<1024, k<64)
__global__ void k_w1t(const float* __restrict__ w, ushort_t* __restrict__ out){
  int i = blockIdx.x * blockDim.x + threadIdx.x;
  if (i < 64 * 1024){ int k = i >> 10, j = i & 1023; out[j * 64 + k] = f2bf(w[i]); }
}
// w2t[j*1024 + k] = w_in[k*4384 + 2048 + j]   (j<2304, k<1024)
__global__ void k_w2t(const float* __restrict__ w_in, ushort_t* __restrict__ out){
  int i = blockIdx.x * blockDim.x + threadIdx.x;
  if (i < 2304 * 1024){
    int k = i / 2304, j = i - k * 2304;
    out[(size_t)j * 1024 + k] = f2bf(w_in[(size_t)k * 4384 + 2048 + j]);
  }
}

// ---------------- bf16 MFMA GEMM: C[M,N] = A[M,K] * Bt[N,K]^T (+bias) ----------------
__device__ __forceinline__ void gload16(const void* g, void* l){
  __builtin_amdgcn_global_load_lds((const __attribute__((address_space(1))) void*)g,
                                   (__attribute__((address_space(3))) void*)l, 16, 0, 0);
}

__global__ __launch_bounds__(256)
void k_gemm_bf16(const ushort_t* __restrict__ A, const ushort_t* __restrict__ Bt,
                 const float* __restrict__ bias, ushort_t* __restrict__ C,
                 int K, int N){
  __shared__ ushort_t tA[128 * 32];
  __shared__ ushort_t tB[128 * 32];
  const int tid  = threadIdx.x;
  const int wave = tid >> 6, lane = tid & 63;
  const int wr = wave >> 1, wc = wave & 1;
  const int l15 = lane & 15, l4 = lane >> 4;
  const int srow  = lane >> 2;        // 0..15
  const int skoff = (lane & 3) * 8;   // 0,8,16,24
  const int m0 = blockIdx.y * 128, n0 = blockIdx.x * 128;

  f32x4 acc[4][4];
  #pragma unroll
  for (int m = 0; m < 4; ++m)
    #pragma unroll
    for (int n = 0; n < 4; ++n)
      #pragma unroll
      for (int r = 0; r < 4; ++r) acc[m][n][r] = 0.f;

  for (int k0 = 0; k0 < K; k0 += 32){
    #pragma unroll
    for (int r = 0; r < 2; ++r){
      int chunk = r * 4 + wave;            // 0..7, 16 rows each
      int rr = chunk * 16 + srow;
      gload16(A  + (size_t)(m0 + rr) * K + k0 + skoff, &tA[chunk * 512]);
      gload16(Bt + (size_t)(n0 + rr) * K + k0 + skoff, &tB[chunk * 512]);
    }
    __syncthreads();
    short8 af[4], bfv[4];
    #pragma unroll
    for (int m = 0; m < 4; ++m)
      af[m] = *(const short8*)&tA[(wr * 64 + m * 16 + l15) * 32 + l4 * 8];
    #pragma unroll
    for (int n = 0; n < 4; ++n)
      bfv[n] = *(const short8*)&tB[(wc * 64 + n * 16 + l15) * 32 + l4 * 8];
    #pragma unroll
    for (int m = 0; m < 4; ++m)
      #pragma unroll
      for (int n = 0; n < 4; ++n)
        acc[m][n] = __builtin_amdgcn_mfma_f32_16x16x32_bf16(af[m], bfv[n], acc[m][n], 0, 0, 0);
    __syncthreads();
  }
  #pragma unroll
  for (int n = 0; n < 4; ++n){
    int col = n0 + wc * 64 + n * 16 + l15;
    float bv = bias ? bias[col] : 0.f;
    #pragma unroll
    for (int m = 0; m < 4; ++m){
      int rowb = m0 + wr * 64 + m * 16 + l4 * 4;
      #pragma unroll
      for (int r = 0; r < 4; ++r)
        C[(size_t)(rowb + r) * N + col] = f2bf(acc[m][n][r] + bv);
    }
  }
}

// ---------------- dt columns in fp32: dt_raw[m,h] = sum_k u[m,k]*w_in[k,4352+h] ----------------
__global__ void k_dt(const ushort_t* __restrict__ u16, const float* __restrict__ w_in,
                     float* __restrict__ dt_raw){
  int r = threadIdx.x >> 5, h = threadIdx.x & 31;
  size_t m = (size_t)blockIdx.x * 8 + r;
  const ushort_t* up = u16 + m * 1024;
  const float* wp = w_in + 4352 + h;
  float acc = 0.f;
  for (int k = 0; k < 1024; k += 4){
    acc += bf2f(up[k])     * wp[(size_t)k * 4384];
    acc += bf2f(up[k + 1]) * wp[(size_t)(k + 1) * 4384];
    acc += bf2f(up[k + 2]) * wp[(size_t)(k + 2) * 4384];
    acc += bf2f(up[k + 3]) * wp[(size_t)(k + 3) * 4384];
  }
  dt_raw[m * 32 + h] = acc;
}

// ---------------- causal depthwise conv (k=4) + SiLU, split outputs ----------------
__global__ void k_conv(const ushort_t* __restrict__ xbc, const float* __restrict__ conv_w,
                       const float* __restrict__ conv_b, ushort_t* __restrict__ xh,
                       float* __restrict__ bmat, float* __restrict__ c_last){
  int row = blockIdx.x;            // b*2048 + t
  int t = row & 2047, b = row >> 11;
  for (int c = threadIdx.x; c < 2304; c += 256){
    float acc = conv_b[c];
    const float* cw = conv_w + c * 4;
    #pragma unroll
    for (int k = 0; k < 4; ++k){
      int tt = t - 3 + k;
      if (tt >= 0) acc += bf2f(xbc[(size_t)(row - 3 + k) * 2304 + c]) * cw[k];
    }
    float s = acc / (1.f + __expf(-acc));   // SiLU
    if (c < 2048)       xh[(size_t)row * 2048 + c] = f2bf(s);
    else if (c < 2176)  bmat[(size_t)row * 128 + (c - 2048)] = s;
    else if (t == 2047) c_last[b * 128 + (c - 2176)] = s;
  }
}

// ---------------- g[b,t] = B_t . C_last ----------------
__global__ void k_gdot(const float* __restrict__ bmat, const float* __restrict__ c_last,
                       float* __restrict__ g){
  int r = threadIdx.x >> 5, n = threadIdx.x & 31;
  int row = blockIdx.x * 8 + r;
  int b = row >> 11;
  const float* bp = bmat + (size_t)row * 128;
  const float* cp = c_last + b * 128;
  float acc = 0.f;
  #pragma unroll
  for (int j = 0; j < 4; ++j) acc += bp[n + 32 * j] * cp[n + 32 * j];
  for (int s = 16; s; s >>= 1) acc += __shfl_down(acc, s, 32);
  if (n == 0) g[row] = acc;
}

// ---------------- per-(b,h) suffix scan -> coeff[t] = exp(S_t)*dt_t*g_t ----------------
__global__ void k_coeff(const float* __restrict__ dt_raw, const float* __restrict__ dt_bias,
                        const float* __restrict__ A_log, const float* __restrict__ g,
                        float* __restrict__ coeffw){
  __shared__ float csum[256];
  int bh = blockIdx.x;             // b*32 + h
  int b = bh >> 5, h = bh & 31;
  float Ah = -__expf(A_log[h]);
  float bias = dt_bias[h];
  int tid = threadIdx.x;
  size_t base = (size_t)b * 2048;
  float d[8], dts[8];
  #pragma unroll
  for (int j = 0; j < 8; ++j){
    int t = tid * 8 + j;
    float x = dt_raw[(base + t) * 32 + h] + bias;
    float sp = (x > 20.f) ? x : log1pf(__expf(x));
    dts[j] = sp;
    d[j] = sp * Ah;
  }
  float cs = 0.f;
  #pragma unroll
  for (int j = 0; j < 8; ++j) cs += d[j];
  csum[tid] = cs;
  __syncthreads();
  float suf = 0.f;
  for (int j = tid + 1; j < 256; ++j) suf += csum[j];
  float S = suf, outv[8];
  for (int j = 7; j >= 0; --j){ outv[j] = S; S += d[j]; }
  #pragma unroll
  for (int j = 0; j < 8; ++j){
    int t = tid * 8 + j;
    coeffw[(size_t)bh * 2048 + t] = __expf(outv[j]) * dts[j] * g[base + t];
  }
}

// ---------------- y_last[b,h,p] = sum_t coeff[b,h,t]*xh[b,t,h,p] + D[h]*xh_last ----------------
__global__ void k_ysum(const float* __restrict__ coeffw, const ushort_t* __restrict__ xh,
                       const float* __restrict__ Dp, float* __restrict__ yfin){
  __shared__ float red[256];
  int bh = blockIdx.x; int b = bh >> 5, h = bh & 31;
  int p = threadIdx.x & 63, stripe = threadIdx.x >> 6;
  const float* cw = coeffw + (size_t)bh * 2048;
  const ushort_t* xp = xh + (size_t)b * 2048 * 2048 + h * 64 + p;
  float acc = 0.f;
  for (int t = stripe; t < 2048; t += 4)
    acc += cw[t] * bf2f(xp[(size_t)t * 2048]);
  red[threadIdx.x] = acc;
  __syncthreads();
  if (stripe == 0){
    float v = red[p] + red[p + 64] + red[p + 128] + red[p + 192];
    v += Dp[h] * bf2f(xp[(size_t)2047 * 2048]);
    yfin[b * 2048 + h * 64 + p] = v;
  }
}

// ---------------- z at last position: z[b,c] = u_last . w_in[:,c], c<2048 ----------------
__global__ void k_zlast(const ushort_t* __restrict__ u16, const float* __restrict__ w_in,
                        float* __restrict__ z_last){
  int b = blockIdx.y; int col = blockIdx.x * 128 + threadIdx.x;
  const ushort_t* up = u16 + ((size_t)b * 2048 + 2047) * 1024;
  float acc = 0.f;
  for (int k = 0; k < 1024; ++k)
    acc += bf2f(up[k]) * w_in[(size_t)k * 4384 + col];
  z_last[b * 2048 + col] = acc;
}

// ---------------- gated RMSNorm ----------------
__global__ void k_norm(const float* __restrict__ yfin, const float* __restrict__ z_last,
                       const float* __restrict__ norm_w, float* __restrict__ yn){
  __shared__ float red[256];
  int b = blockIdx.x, tid = threadIdx.x;
  float vals[8], ss = 0.f;
  #pragma unroll
  for (int j = 0; j < 8; ++j){
    int c = tid + 256 * j;
    float z = z_last[b * 2048 + c];
    float yg = yfin[b * 2048 + c] * (z / (1.f + __expf(-z)));
    vals[j] = yg; ss += yg * yg;
  }
  red[tid] = ss; __syncthreads();
  for (int s = 128; s; s >>= 1){
    if (tid < s) red[tid] += red[tid + s];
    __syncthreads();
  }
  float scale = rsqrtf(red[0] / 2048.f + EPSV);
  #pragma unroll
  for (int j = 0; j < 8; ++j){
    int c = tid + 256 * j;
    yn[b * 2048 + c] = vals[j] * scale * norm_w[c];
  }
}

// ---------------- out projection (last row only): o[b,j] = yn . w_out[:,j] ----------------
__global__ void k_outproj(const float* __restrict__ yn, const float* __restrict__ w_out,
                          float* __restrict__ o){
  int b = blockIdx.y; int col = blockIdx.x * 128 + threadIdx.x;
  const float* yp = yn + b * 2048;
  float acc = 0.f;
  for (int k = 0; k < 2048; ++k)
    acc += yp[k] * w_out[(size_t)k * 1024 + col];
  o[b * 1024 + col] = acc;
}

// ---------------- head: logits[b,j] = o . w_head[:,j] + b_head[j] ----------------
__global__ void k_head(const float* __restrict__ o, const float* __restrict__ w_head,
                       const float* __restrict__ b_head, float* __restrict__ out){
  int b = blockIdx.x, j = threadIdx.x;
  const float* op = o + b * 1024;
  float acc = b_head[j];
  for (int k = 0; k < 1024; ++k) acc += op[k] * w_head[k * 64 + j];
  out[b * 64 + j] = acc;
}

extern "C" void kernel_launch(void* const* d_in, const int* in_sizes, int n_in,
                              void* d_out, int out_size, void* d_ws, size_t ws_size,
                              hipStream_t stream){
  (void)in_sizes; (void)n_in; (void)out_size; (void)ws_size;
  const float* x       = (const float*)d_in[0];
  const float* w_proj  = (const float*)d_in[1];
  const float* b_proj  = (const float*)d_in[2];
  const float* w_in    = (const float*)d_in[3];
  const float* conv_w  = (const float*)d_in[4];
  const float* conv_b  = (const float*)d_in[5];
  const float* A_log   = (const float*)d_in[6];
  const float* dt_bias = (const float*)d_in[7];
  const float* Dp      = (const float*)d_in[8];
  const float* norm_w  = (const float*)d_in[9];
  const float* w_out   = (const float*)d_in[10];
  const float* w_head  = (const float*)d_in[11];
  const float* b_head  = (const float*)d_in[12];
  float* out = (float*)d_out;

  char* ws = (char*)d_ws;
  size_t off = 0;
  auto alloc = [&](size_t bytes)->char*{
    char* p = ws + off; off += (bytes + 255) & ~(size_t)255; return p;
  };
  ushort_t* xb    = (ushort_t*)alloc((size_t)M_ROWS * 64 * 2);
  ushort_t* w1t   = (ushort_t*)alloc((size_t)1024 * 64 * 2);
  ushort_t* w2t   = (ushort_t*)alloc((size_t)2304 * 1024 * 2);
  ushort_t* u16   = (ushort_t*)alloc((size_t)M_ROWS * 1024 * 2);
  ushort_t* xbc   = (ushort_t*)alloc((size_t)M_ROWS * 2304 * 2);
  float*    dtr   = (float*)alloc((size_t)M_ROWS * 32 * 4);
  ushort_t* xh    = (ushort_t*)alloc((size_t)M_ROWS * 2048 * 2);
  float*    bmat  = (float*)alloc((size_t)M_ROWS * 128 * 4);
  float*    clast = (float*)alloc((size_t)8 * 128 * 4);
  float*    g     = (float*)alloc((size_t)M_ROWS * 4);
  float*    cfw   = (float*)alloc((size_t)256 * 2048 * 4);
  float*    yfin  = (float*)alloc((size_t)8 * 2048 * 4);
  float*    zl    = (float*)alloc((size_t)8 * 2048 * 4);
  float*    yn    = (float*)alloc((size_t)8 * 2048 * 4);
  float*    ov    = (float*)alloc((size_t)8 * 1024 * 4);

  k_cvt_bf16<<<(M_ROWS * 64 + 255) / 256, 256, 0, stream>>>(x, xb, M_ROWS * 64);
  k_w1t<<<(65536 + 255) / 256, 256, 0, stream>>>(w_proj, w1t);
  k_w2t<<<(2304 * 1024 + 255) / 256, 256, 0, stream>>>(w_in, w2t);

  dim3 g1(1024 / 128, M_ROWS / 128);
  k_gemm_bf16<<<g1, 256, 0, stream>>>(xb, w1t, b_proj, u16, 64, 1024);
  dim3 g2(2304 / 128, M_ROWS / 128);
  k_gemm_bf16<<<g2, 256, 0, stream>>>(u16, w2t, nullptr, xbc, 1024, 2304);

  k_dt<<<M_ROWS / 8, 256, 0, stream>>>(u16, w_in, dtr);
  k_conv<<<M_ROWS, 256, 0, stream>>>(xbc, conv_w, conv_b, xh, bmat, clast);
  k_gdot<<<M_ROWS / 8, 256, 0, stream>>>(bmat, clast, g);
  k_coeff<<<256, 256, 0, stream>>>(dtr, dt_bias, A_log, g, cfw);
  k_ysum<<<256, 256, 0, stream>>>(cfw, xh, Dp, yfin);

  dim3 gz(16, 8);
  k_zlast<<<gz, 128, 0, stream>>>(u16, w_in, zl);
  k_norm<<<8, 256, 0, stream>>>(yfin, zl, norm_w, yn);
  dim3 go(8, 8);
  k_outproj<<<go, 128, 0, stream>>>(yn, w_out, ov);
  k_head<<<8, 64, 0, stream>>>(ov, w_head, b_head, out);
}

// Round 2
// 414.789 us; speedup vs baseline: 1.8289x; 1.8289x over previous
//
#include <hip/hip_runtime.h>
#include <hip/hip_bf16.h>
#include <stdint.h>

typedef unsigned short ushort_t;
typedef __attribute__((ext_vector_type(8))) short short8;
typedef __attribute__((ext_vector_type(4))) short short4v;
typedef __attribute__((ext_vector_type(4))) unsigned short ushort4v;
typedef __attribute__((ext_vector_type(4))) float f32x4;

#define L_SEQ   2048
#define BATCH   8
#define M_ROWS  16384          // BATCH*L_SEQ
#define DMODEL  1024
#define DINNER  2048
#define DSTATE  128
#define NHEADS  32
#define HEADDIM 64
#define CONVDIM 2304
#define DINPROJ 4384
#define EPSV    1e-5f
#define TCH     64             // conv time-chunk

__device__ __forceinline__ float bf2f(ushort_t u){
  union { uint32_t i; float f; } v; v.i = ((uint32_t)u) << 16; return v.f;
}
__device__ __forceinline__ ushort_t f2bf(float f){
  union { float f; uint32_t i; } v; v.f = f;
  uint32_t r = v.i + 0x7fffu + ((v.i >> 16) & 1u);
  return (ushort_t)(r >> 16);
}

// ---------------- conversion / transpose kernels ----------------
__global__ void k_cvt_bf16(const float* __restrict__ src, ushort_t* __restrict__ dst, int n){
  int i = blockIdx.x * blockDim.x + threadIdx.x;
  if (i < n) dst[i] = f2bf(src[i]);
}
// w1t[j*64 + k] = w_proj[k*1024 + j]   (j<1024, k<64) — tiny, keep simple
__global__ void k_w1t(const float* __restrict__ w, ushort_t* __restrict__ out){
  int i = blockIdx.x * blockDim.x + threadIdx.x;
  if (i < 64 * 1024){ int k = i >> 10, j = i & 1023; out[j * 64 + k] = f2bf(w[i]); }
}
// LDS-tiled transpose: w2t[j*1024 + k] = w_in[k*4384 + 2048 + j]  (j<2304, k<1024)
__global__ __launch_bounds__(256)
void k_w2t(const float* __restrict__ w_in, ushort_t* __restrict__ out){
  __shared__ float tile[64][65];
  int j0 = blockIdx.x * 64;          // 36 tiles
  int k0 = blockIdx.y * 64;          // 16 tiles
  int tx = threadIdx.x & 63, ty = threadIdx.x >> 6;
  #pragma unroll
  for (int i = 0; i < 16; ++i){
    int kk = ty * 16 + i;
    tile[kk][tx] = w_in[(size_t)(k0 + kk) * 4384 + 2048 + j0 + tx];
  }
  __syncthreads();
  #pragma unroll
  for (int i = 0; i < 16; ++i){
    int jj = ty * 16 + i;
    out[(size_t)(j0 + jj) * 1024 + k0 + tx] = f2bf(tile[tx][jj]);
  }
}
// dt weights hi/lo split, transposed: wdt[n*2048 + k](hi), wdt[n*2048+1024+k](lo)
__global__ void k_wdt(const float* __restrict__ w_in, ushort_t* __restrict__ wdt){
  int i = blockIdx.x * blockDim.x + threadIdx.x;
  if (i < 32 * 1024){
    int n = i >> 10, k = i & 1023;
    float w = w_in[(size_t)k * 4384 + 4352 + n];
    ushort_t hi = f2bf(w);
    float lo = w - bf2f(hi);
    wdt[n * 2048 + k] = hi;
    wdt[n * 2048 + 1024 + k] = f2bf(lo);
  }
}

// ---------------- bf16 MFMA GEMM: C[M,N] = A[M,K] * Bt[N,K]^T (+bias) ----------------
__device__ __forceinline__ void gload16(const void* g, void* l){
  __builtin_amdgcn_global_load_lds((const __attribute__((address_space(1))) void*)g,
                                   (__attribute__((address_space(3))) void*)l, 16, 0, 0);
}

__global__ __launch_bounds__(256)
void k_gemm_bf16(const ushort_t* __restrict__ A, const ushort_t* __restrict__ Bt,
                 const float* __restrict__ bias, ushort_t* __restrict__ C,
                 int K, int N){
  __shared__ ushort_t tA[128 * 32];
  __shared__ ushort_t tB[128 * 32];
  const int tid  = threadIdx.x;
  const int wave = tid >> 6, lane = tid & 63;
  const int wr = wave >> 1, wc = wave & 1;
  const int l15 = lane & 15, l4 = lane >> 4;
  const int srow  = lane >> 2;        // 0..15
  const int skoff = (lane & 3) * 8;   // 0,8,16,24
  const int m0 = blockIdx.y * 128, n0 = blockIdx.x * 128;

  f32x4 acc[4][4];
  #pragma unroll
  for (int m = 0; m < 4; ++m)
    #pragma unroll
    for (int n = 0; n < 4; ++n)
      #pragma unroll
      for (int r = 0; r < 4; ++r) acc[m][n][r] = 0.f;

  for (int k0 = 0; k0 < K; k0 += 32){
    #pragma unroll
    for (int r = 0; r < 2; ++r){
      int chunk = r * 4 + wave;            // 0..7, 16 rows each
      int rr = chunk * 16 + srow;
      gload16(A  + (size_t)(m0 + rr) * K + k0 + skoff, &tA[chunk * 512]);
      gload16(Bt + (size_t)(n0 + rr) * K + k0 + skoff, &tB[chunk * 512]);
    }
    __syncthreads();
    short8 af[4], bfv[4];
    #pragma unroll
    for (int m = 0; m < 4; ++m)
      af[m] = *(const short8*)&tA[(wr * 64 + m * 16 + l15) * 32 + l4 * 8];
    #pragma unroll
    for (int n = 0; n < 4; ++n)
      bfv[n] = *(const short8*)&tB[(wc * 64 + n * 16 + l15) * 32 + l4 * 8];
    #pragma unroll
    for (int m = 0; m < 4; ++m)
      #pragma unroll
      for (int n = 0; n < 4; ++n)
        acc[m][n] = __builtin_amdgcn_mfma_f32_16x16x32_bf16(af[m], bfv[n], acc[m][n], 0, 0, 0);
    __syncthreads();
  }
  #pragma unroll
  for (int n = 0; n < 4; ++n){
    int col = n0 + wc * 64 + n * 16 + l15;
    float bv = bias ? bias[col] : 0.f;
    #pragma unroll
    for (int m = 0; m < 4; ++m){
      int rowb = m0 + wr * 64 + m * 16 + l4 * 4;
      #pragma unroll
      for (int r = 0; r < 4; ++r)
        C[(size_t)(rowb + r) * N + col] = f2bf(acc[m][n][r] + bv);
    }
  }
}

// ---------------- dt GEMM (fp32 out): dtr[m,n] = sum_{k<2048} u[m, k&1023] * wdt[n,k] ----------------
// wdt holds [hi | lo] along K so fp32 MFMA accumulation reproduces fp32-weight precision.
__global__ __launch_bounds__(256)
void k_dtg(const ushort_t* __restrict__ A, const ushort_t* __restrict__ Bt,
           float* __restrict__ dtr){
  __shared__ ushort_t tA[128 * 32];
  __shared__ ushort_t tB[32 * 32];
  const int tid  = threadIdx.x;
  const int wave = tid >> 6, lane = tid & 63;
  const int l15 = lane & 15, l4 = lane >> 4;
  const int srow  = lane >> 2;
  const int skoff = (lane & 3) * 8;
  const int m0 = blockIdx.x * 128;

  f32x4 acc[2][2];
  #pragma unroll
  for (int m = 0; m < 2; ++m)
    #pragma unroll
    for (int n = 0; n < 2; ++n)
      #pragma unroll
      for (int r = 0; r < 4; ++r) acc[m][n][r] = 0.f;

  for (int k0 = 0; k0 < 2048; k0 += 32){
    int ks = k0 & 1023;
    #pragma unroll
    for (int r = 0; r < 2; ++r){
      int chunk = r * 4 + wave;
      int rr = chunk * 16 + srow;
      gload16(A + (size_t)(m0 + rr) * 1024 + ks + skoff, &tA[chunk * 512]);
    }
    if (wave < 2){
      int rr = wave * 16 + srow;
      gload16(Bt + (size_t)rr * 2048 + k0 + skoff, &tB[wave * 512]);
    }
    __syncthreads();
    short8 af[2], bfv[2];
    #pragma unroll
    for (int m = 0; m < 2; ++m)
      af[m] = *(const short8*)&tA[(wave * 32 + m * 16 + l15) * 32 + l4 * 8];
    #pragma unroll
    for (int n = 0; n < 2; ++n)
      bfv[n] = *(const short8*)&tB[(n * 16 + l15) * 32 + l4 * 8];
    #pragma unroll
    for (int m = 0; m < 2; ++m)
      #pragma unroll
      for (int n = 0; n < 2; ++n)
        acc[m][n] = __builtin_amdgcn_mfma_f32_16x16x32_bf16(af[m], bfv[n], acc[m][n], 0, 0, 0);
    __syncthreads();
  }
  #pragma unroll
  for (int n = 0; n < 2; ++n){
    int col = n * 16 + l15;
    #pragma unroll
    for (int m = 0; m < 2; ++m){
      int rowb = m0 + wave * 32 + m * 16 + l4 * 4;
      #pragma unroll
      for (int r = 0; r < 4; ++r)
        dtr[(size_t)(rowb + r) * 32 + col] = acc[m][n][r];
    }
  }
}

// ---------------- causal depthwise conv (k=4) + SiLU: time-iterating, 4ch/thread ----------------
__global__ __launch_bounds__(192)
void k_conv(const ushort_t* __restrict__ xbc, const float* __restrict__ conv_w,
            const float* __restrict__ conv_b, ushort_t* __restrict__ xh,
            float* __restrict__ bmat, float* __restrict__ c_last){
  const int c0 = (blockIdx.x * 192 + threadIdx.x) * 4;   // 3 * 768 = 2304 channels
  const int t0 = blockIdx.y * TCH;
  const int b  = blockIdx.z;
  const size_t rowbase = (size_t)b * 2048;

  float cw[4][4], cb[4];
  #pragma unroll
  for (int j = 0; j < 4; ++j){
    cb[j] = conv_b[c0 + j];
    #pragma unroll
    for (int k = 0; k < 4; ++k) cw[j][k] = conv_w[(c0 + j) * 4 + k];
  }
  float h[3][4];
  #pragma unroll
  for (int k = 0; k < 3; ++k){
    int tt = t0 - 3 + k;
    if (tt >= 0){
      short4v v = *(const short4v*)&xbc[(rowbase + tt) * 2304 + c0];
      #pragma unroll
      for (int j = 0; j < 4; ++j) h[k][j] = bf2f((ushort_t)v[j]);
    } else {
      #pragma unroll
      for (int j = 0; j < 4; ++j) h[k][j] = 0.f;
    }
  }
  for (int t = t0; t < t0 + TCH; ++t){
    short4v v = *(const short4v*)&xbc[(rowbase + t) * 2304 + c0];
    float outv[4];
    #pragma unroll
    for (int j = 0; j < 4; ++j){
      float x = bf2f((ushort_t)v[j]);
      float a = cb[j] + h[0][j] * cw[j][0] + h[1][j] * cw[j][1] + h[2][j] * cw[j][2] + x * cw[j][3];
      outv[j] = a / (1.f + __expf(-a));
      h[0][j] = h[1][j]; h[1][j] = h[2][j]; h[2][j] = x;
    }
    if (c0 < 2048){
      ushort4v o;
      #pragma unroll
      for (int j = 0; j < 4; ++j) o[j] = f2bf(outv[j]);
      *(ushort4v*)&xh[(rowbase + t) * 2048 + c0] = o;
    } else if (c0 < 2176){
      f32x4 o;
      #pragma unroll
      for (int j = 0; j < 4; ++j) o[j] = outv[j];
      *(f32x4*)&bmat[(rowbase + t) * 128 + (c0 - 2048)] = o;
    } else if (t == 2047){
      f32x4 o;
      #pragma unroll
      for (int j = 0; j < 4; ++j) o[j] = outv[j];
      *(f32x4*)&c_last[b * 128 + (c0 - 2176)] = o;
    }
  }
}

// ---------------- g[b,t] = B_t . C_last ----------------
__global__ void k_gdot(const float* __restrict__ bmat, const float* __restrict__ c_last,
                       float* __restrict__ g){
  int r = threadIdx.x >> 5, n = threadIdx.x & 31;
  int row = blockIdx.x * 8 + r;
  int b = row >> 11;
  const float* bp = bmat + (size_t)row * 128;
  const float* cp = c_last + b * 128;
  float acc = 0.f;
  #pragma unroll
  for (int j = 0; j < 4; ++j) acc += bp[n + 32 * j] * cp[n + 32 * j];
  for (int s = 16; s; s >>= 1) acc += __shfl_down(acc, s, 32);
  if (n == 0) g[row] = acc;
}

// ---------------- per-(b,h) suffix scan -> coeff[t] = exp(S_t)*dt_t*g_t ----------------
__global__ void k_coeff(const float* __restrict__ dt_raw, const float* __restrict__ dt_bias,
                        const float* __restrict__ A_log, const float* __restrict__ g,
                        float* __restrict__ coeffw){
  __shared__ float csum[256];
  int bh = blockIdx.x;             // b*32 + h
  int b = bh >> 5, h = bh & 31;
  float Ah = -__expf(A_log[h]);
  float bias = dt_bias[h];
  int tid = threadIdx.x;
  size_t base = (size_t)b * 2048;
  float d[8], dts[8];
  #pragma unroll
  for (int j = 0; j < 8; ++j){
    int t = tid * 8 + j;
    float x = dt_raw[(base + t) * 32 + h] + bias;
    float sp = (x > 20.f) ? x : log1pf(__expf(x));
    dts[j] = sp;
    d[j] = sp * Ah;
  }
  float cs = 0.f;
  #pragma unroll
  for (int j = 0; j < 8; ++j) cs += d[j];
  csum[tid] = cs;
  __syncthreads();
  float suf = 0.f;
  for (int j = tid + 1; j < 256; ++j) suf += csum[j];
  float S = suf, outv[8];
  for (int j = 7; j >= 0; --j){ outv[j] = S; S += d[j]; }
  #pragma unroll
  for (int j = 0; j < 8; ++j){
    int t = tid * 8 + j;
    coeffw[(size_t)bh * 2048 + t] = __expf(outv[j]) * dts[j] * g[base + t];
  }
}

// ---------------- y_last partials: ypart[bh,chunk,p] = sum_{t in chunk} coeff*xh ----------------
__global__ void k_ysum_p(const float* __restrict__ coeffw, const ushort_t* __restrict__ xh,
                         float* __restrict__ ypart){
  __shared__ float red[256];
  int bh = blockIdx.x, ch = blockIdx.y;
  int b = bh >> 5, h = bh & 31;
  int p = threadIdx.x & 63, stripe = threadIdx.x >> 6;
  const float* cw = coeffw + (size_t)bh * 2048 + ch * 256;
  const ushort_t* xp = xh + ((size_t)b * 2048 + ch * 256) * 2048 + h * 64 + p;
  float acc = 0.f;
  for (int t = stripe; t < 256; t += 4)
    acc += cw[t] * bf2f(xp[(size_t)t * 2048]);
  red[threadIdx.x] = acc;
  __syncthreads();
  if (stripe == 0)
    ypart[((size_t)bh * 8 + ch) * 64 + p] = red[p] + red[p + 64] + red[p + 128] + red[p + 192];
}
__global__ void k_ysum_r(const float* __restrict__ ypart, const ushort_t* __restrict__ xh,
                         const float* __restrict__ Dp, float* __restrict__ yfin){
  int i = blockIdx.x * 256 + threadIdx.x;      // 16384
  int bh = i >> 6, p = i & 63;
  int b = bh >> 5, h = bh & 31;
  float v = 0.f;
  #pragma unroll
  for (int c = 0; c < 8; ++c) v += ypart[((size_t)bh * 8 + c) * 64 + p];
  v += Dp[h] * bf2f(xh[((size_t)b * 2048 + 2047) * 2048 + h * 64 + p]);
  yfin[b * 2048 + h * 64 + p] = v;
}

// ---------------- z at last position: z[b,c] = u_last . w_in[:,c], c<2048 ----------------
__global__ void k_zlast(const ushort_t* __restrict__ u16, const float* __restrict__ w_in,
                        float* __restrict__ z_last){
  int b = blockIdx.y; int col = blockIdx.x * 128 + threadIdx.x;
  const ushort_t* up = u16 + ((size_t)b * 2048 + 2047) * 1024;
  float acc = 0.f;
  for (int k = 0; k < 1024; ++k)
    acc += bf2f(up[k]) * w_in[(size_t)k * 4384 + col];
  z_last[b * 2048 + col] = acc;
}

// ---------------- gated RMSNorm ----------------
__global__ void k_norm(const float* __restrict__ yfin, const float* __restrict__ z_last,
                       const float* __restrict__ norm_w, float* __restrict__ yn){
  __shared__ float red[256];
  int b = blockIdx.x, tid = threadIdx.x;
  float vals[8], ss = 0.f;
  #pragma unroll
  for (int j = 0; j < 8; ++j){
    int c = tid + 256 * j;
    float z = z_last[b * 2048 + c];
    float yg = yfin[b * 2048 + c] * (z / (1.f + __expf(-z)));
    vals[j] = yg; ss += yg * yg;
  }
  red[tid] = ss; __syncthreads();
  for (int s = 128; s; s >>= 1){
    if (tid < s) red[tid] += red[tid + s];
    __syncthreads();
  }
  float scale = rsqrtf(red[0] / 2048.f + EPSV);
  #pragma unroll
  for (int j = 0; j < 8; ++j){
    int c = tid + 256 * j;
    yn[b * 2048 + c] = vals[j] * scale * norm_w[c];
  }
}

// ---------------- out projection (last row only) ----------------
__global__ void k_outproj(const float* __restrict__ yn, const float* __restrict__ w_out,
                          float* __restrict__ o){
  int b = blockIdx.y; int col = blockIdx.x * 128 + threadIdx.x;
  const float* yp = yn + b * 2048;
  float acc = 0.f;
  for (int k = 0; k < 2048; ++k)
    acc += yp[k] * w_out[(size_t)k * 1024 + col];
  o[b * 1024 + col] = acc;
}

// ---------------- head ----------------
__global__ void k_head(const float* __restrict__ o, const float* __restrict__ w_head,
                       const float* __restrict__ b_head, float* __restrict__ out){
  int b = blockIdx.x, j = threadIdx.x;
  const float* op = o + b * 1024;
  float acc = b_head[j];
  for (int k = 0; k < 1024; ++k) acc += op[k] * w_head[k * 64 + j];
  out[b * 64 + j] = acc;
}

extern "C" void kernel_launch(void* const* d_in, const int* in_sizes, int n_in,
                              void* d_out, int out_size, void* d_ws, size_t ws_size,
                              hipStream_t stream){
  (void)in_sizes; (void)n_in; (void)out_size; (void)ws_size;
  const float* x       = (const float*)d_in[0];
  const float* w_proj  = (const float*)d_in[1];
  const float* b_proj  = (const float*)d_in[2];
  const float* w_in    = (const float*)d_in[3];
  const float* conv_w  = (const float*)d_in[4];
  const float* conv_b  = (const float*)d_in[5];
  const float* A_log   = (const float*)d_in[6];
  const float* dt_bias = (const float*)d_in[7];
  const float* Dp      = (const float*)d_in[8];
  const float* norm_w  = (const float*)d_in[9];
  const float* w_out   = (const float*)d_in[10];
  const float* w_head  = (const float*)d_in[11];
  const float* b_head  = (const float*)d_in[12];
  float* out = (float*)d_out;

  char* ws = (char*)d_ws;
  size_t off = 0;
  auto alloc = [&](size_t bytes)->char*{
    char* p = ws + off; off += (bytes + 255) & ~(size_t)255; return p;
  };
  ushort_t* xb    = (ushort_t*)alloc((size_t)M_ROWS * 64 * 2);
  ushort_t* w1t   = (ushort_t*)alloc((size_t)1024 * 64 * 2);
  ushort_t* w2t   = (ushort_t*)alloc((size_t)2304 * 1024 * 2);
  ushort_t* wdt   = (ushort_t*)alloc((size_t)32 * 2048 * 2);
  ushort_t* u16   = (ushort_t*)alloc((size_t)M_ROWS * 1024 * 2);
  ushort_t* xbc   = (ushort_t*)alloc((size_t)M_ROWS * 2304 * 2);
  float*    dtr   = (float*)alloc((size_t)M_ROWS * 32 * 4);
  ushort_t* xh    = (ushort_t*)alloc((size_t)M_ROWS * 2048 * 2);
  float*    bmat  = (float*)alloc((size_t)M_ROWS * 128 * 4);
  float*    clast = (float*)alloc((size_t)8 * 128 * 4);
  float*    g     = (float*)alloc((size_t)M_ROWS * 4);
  float*    cfw   = (float*)alloc((size_t)256 * 2048 * 4);
  float*    ypart = (float*)alloc((size_t)256 * 8 * 64 * 4);
  float*    yfin  = (float*)alloc((size_t)8 * 2048 * 4);
  float*    zl    = (float*)alloc((size_t)8 * 2048 * 4);
  float*    yn    = (float*)alloc((size_t)8 * 2048 * 4);
  float*    ov    = (float*)alloc((size_t)8 * 1024 * 4);

  k_cvt_bf16<<<(M_ROWS * 64 + 255) / 256, 256, 0, stream>>>(x, xb, M_ROWS * 64);
  k_w1t<<<(65536 + 255) / 256, 256, 0, stream>>>(w_proj, w1t);
  dim3 gw2(36, 16);
  k_w2t<<<gw2, 256, 0, stream>>>(w_in, w2t);
  k_wdt<<<(32768 + 255) / 256, 256, 0, stream>>>(w_in, wdt);

  dim3 g1(1024 / 128, M_ROWS / 128);
  k_gemm_bf16<<<g1, 256, 0, stream>>>(xb, w1t, b_proj, u16, 64, 1024);
  dim3 g2(2304 / 128, M_ROWS / 128);
  k_gemm_bf16<<<g2, 256, 0, stream>>>(u16, w2t, nullptr, xbc, 1024, 2304);

  k_dtg<<<M_ROWS / 128, 256, 0, stream>>>(u16, wdt, dtr);

  dim3 gc(3, L_SEQ / TCH, BATCH);
  k_conv<<<gc, 192, 0, stream>>>(xbc, conv_w, conv_b, xh, bmat, clast);

  k_gdot<<<M_ROWS / 8, 256, 0, stream>>>(bmat, clast, g);
  k_coeff<<<256, 256, 0, stream>>>(dtr, dt_bias, A_log, g, cfw);

  dim3 gy(256, 8);
  k_ysum_p<<<gy, 256, 0, stream>>>(cfw, xh, ypart);
  k_ysum_r<<<M_ROWS / 256, 256, 0, stream>>>(ypart, xh, Dp, yfin);

  dim3 gz(16, 8);
  k_zlast<<<gz, 128, 0, stream>>>(u16, w_in, zl);
  k_norm<<<8, 256, 0, stream>>>(yfin, zl, norm_w, yn);
  dim3 go(8, 8);
  k_outproj<<<go, 128, 0, stream>>>(yn, w_out, ov);
  k_head<<<8, 64, 0, stream>>>(ov, w_head, b_head, out);
}

// Round 3
// 280.539 us; speedup vs baseline: 2.7041x; 1.4785x over previous
//
#include <hip/hip_runtime.h>
#include <hip/hip_bf16.h>
#include <stdint.h>

typedef unsigned short ushort_t;
typedef __attribute__((ext_vector_type(8))) short short8;
typedef __attribute__((ext_vector_type(4))) short short4v;
typedef __attribute__((ext_vector_type(4))) unsigned short ushort4v;
typedef __attribute__((ext_vector_type(4))) float f32x4;

#define L_SEQ   2048
#define BATCH   8
#define M_ROWS  16384          // BATCH*L_SEQ
#define DMODEL  1024
#define DINNER  2048
#define DSTATE  128
#define NHEADS  32
#define HEADDIM 64
#define CONVDIM 2304
#define DINPROJ 4384
#define EPSV    1e-5f
#define TCH     64             // conv time-chunk

__device__ __forceinline__ float bf2f(ushort_t u){
  union { uint32_t i; float f; } v; v.i = ((uint32_t)u) << 16; return v.f;
}
__device__ __forceinline__ ushort_t f2bf(float f){
  union { float f; uint32_t i; } v; v.f = f;
  uint32_t r = v.i + 0x7fffu + ((v.i >> 16) & 1u);
  return (ushort_t)(r >> 16);
}

// ---------------- conversion / transpose kernels ----------------
__global__ void k_cvt_bf16(const float* __restrict__ src, ushort_t* __restrict__ dst, int n){
  int i = blockIdx.x * blockDim.x + threadIdx.x;
  if (i < n) dst[i] = f2bf(src[i]);
}
// w1t[j*64 + k] = w_proj[k*1024 + j]   (j<1024, k<64)
__global__ void k_w1t(const float* __restrict__ w, ushort_t* __restrict__ out){
  int i = blockIdx.x * blockDim.x + threadIdx.x;
  if (i < 64 * 1024){ int k = i >> 10, j = i & 1023; out[j * 64 + k] = f2bf(w[i]); }
}
// LDS-tiled transpose to bf16: w2t[j*1024 + k] = w_in[k*4384 + 2048 + j]
__global__ __launch_bounds__(256)
void k_w2t(const float* __restrict__ w_in, ushort_t* __restrict__ out){
  __shared__ float tile[64][65];
  int j0 = blockIdx.x * 64;          // 36 tiles
  int k0 = blockIdx.y * 64;          // 16 tiles
  int tx = threadIdx.x & 63, ty = threadIdx.x >> 6;
  #pragma unroll
  for (int i = 0; i < 16; ++i){
    int kk = ty * 16 + i;
    tile[kk][tx] = w_in[(size_t)(k0 + kk) * 4384 + 2048 + j0 + tx];
  }
  __syncthreads();
  #pragma unroll
  for (int i = 0; i < 16; ++i){
    int jj = ty * 16 + i;
    out[(size_t)(j0 + jj) * 1024 + k0 + tx] = f2bf(tile[tx][jj]);
  }
}
// generic fp32 LDS-tiled transpose: dst[j*R + k] = src[k*C + colOff + j]; R,Cn multiples of 64
__global__ __launch_bounds__(256)
void k_transf32(const float* __restrict__ src, float* __restrict__ dst,
                int R, int C, int colOff){
  __shared__ float tile[64][65];
  int j0 = blockIdx.x * 64;
  int k0 = blockIdx.y * 64;
  int tx = threadIdx.x & 63, ty = threadIdx.x >> 6;
  #pragma unroll
  for (int i = 0; i < 16; ++i){
    int kk = ty * 16 + i;
    tile[kk][tx] = src[(size_t)(k0 + kk) * C + colOff + j0 + tx];
  }
  __syncthreads();
  #pragma unroll
  for (int i = 0; i < 16; ++i){
    int jj = ty * 16 + i;
    dst[(size_t)(j0 + jj) * R + k0 + tx] = tile[tx][jj];
  }
}
// dt weights hi/lo split, transposed: wdt[n*2048 + k](hi), wdt[n*2048+1024+k](lo)
__global__ void k_wdt(const float* __restrict__ w_in, ushort_t* __restrict__ wdt){
  int i = blockIdx.x * blockDim.x + threadIdx.x;
  if (i < 32 * 1024){
    int n = i >> 10, k = i & 1023;
    float w = w_in[(size_t)k * 4384 + 4352 + n];
    ushort_t hi = f2bf(w);
    float lo = w - bf2f(hi);
    wdt[n * 2048 + k] = hi;
    wdt[n * 2048 + 1024 + k] = f2bf(lo);
  }
}

// ---------------- bf16 MFMA GEMM: C[M,N] = A[M,K] * Bt[N,K]^T (+bias) ----------------
__device__ __forceinline__ void gload16(const void* g, void* l){
  __builtin_amdgcn_global_load_lds((const __attribute__((address_space(1))) void*)g,
                                   (__attribute__((address_space(3))) void*)l, 16, 0, 0);
}

__global__ __launch_bounds__(256)
void k_gemm_bf16(const ushort_t* __restrict__ A, const ushort_t* __restrict__ Bt,
                 const float* __restrict__ bias, ushort_t* __restrict__ C,
                 int K, int N, int nbx){
  __shared__ ushort_t tA[128 * 32];
  __shared__ ushort_t tB[128 * 32];
  // XCD-aware bijective swizzle (gridDim.x % 8 == 0)
  const int nwg = gridDim.x;
  const int cpx = nwg >> 3;
  const int bid = blockIdx.x;
  const int swz = (bid & 7) * cpx + (bid >> 3);
  const int m0 = (swz / nbx) * 128, n0 = (swz % nbx) * 128;

  const int tid  = threadIdx.x;
  const int wave = tid >> 6, lane = tid & 63;
  const int wr = wave >> 1, wc = wave & 1;
  const int l15 = lane & 15, l4 = lane >> 4;
  const int srow  = lane >> 2;        // 0..15
  const int skoff = (lane & 3) * 8;   // 0,8,16,24

  f32x4 acc[4][4];
  #pragma unroll
  for (int m = 0; m < 4; ++m)
    #pragma unroll
    for (int n = 0; n < 4; ++n)
      #pragma unroll
      for (int r = 0; r < 4; ++r) acc[m][n][r] = 0.f;

  for (int k0 = 0; k0 < K; k0 += 32){
    #pragma unroll
    for (int r = 0; r < 2; ++r){
      int chunk = r * 4 + wave;            // 0..7, 16 rows each
      int rr = chunk * 16 + srow;
      gload16(A  + (size_t)(m0 + rr) * K + k0 + skoff, &tA[chunk * 512]);
      gload16(Bt + (size_t)(n0 + rr) * K + k0 + skoff, &tB[chunk * 512]);
    }
    __syncthreads();
    short8 af[4], bfv[4];
    #pragma unroll
    for (int m = 0; m < 4; ++m)
      af[m] = *(const short8*)&tA[(wr * 64 + m * 16 + l15) * 32 + l4 * 8];
    #pragma unroll
    for (int n = 0; n < 4; ++n)
      bfv[n] = *(const short8*)&tB[(wc * 64 + n * 16 + l15) * 32 + l4 * 8];
    #pragma unroll
    for (int m = 0; m < 4; ++m)
      #pragma unroll
      for (int n = 0; n < 4; ++n)
        acc[m][n] = __builtin_amdgcn_mfma_f32_16x16x32_bf16(af[m], bfv[n], acc[m][n], 0, 0, 0);
    __syncthreads();
  }
  #pragma unroll
  for (int n = 0; n < 4; ++n){
    int col = n0 + wc * 64 + n * 16 + l15;
    float bv = bias ? bias[col] : 0.f;
    #pragma unroll
    for (int m = 0; m < 4; ++m){
      int rowb = m0 + wr * 64 + m * 16 + l4 * 4;
      #pragma unroll
      for (int r = 0; r < 4; ++r)
        C[(size_t)(rowb + r) * N + col] = f2bf(acc[m][n][r] + bv);
    }
  }
}

// ---------------- dt GEMM (fp32 out): dtr[m,n] = sum_{k<2048} u[m, k&1023] * wdt[n,k] ----------------
__global__ __launch_bounds__(256)
void k_dtg(const ushort_t* __restrict__ A, const ushort_t* __restrict__ Bt,
           float* __restrict__ dtr){
  __shared__ ushort_t tA[128 * 32];
  __shared__ ushort_t tB[32 * 32];
  const int tid  = threadIdx.x;
  const int wave = tid >> 6, lane = tid & 63;
  const int l15 = lane & 15, l4 = lane >> 4;
  const int srow  = lane >> 2;
  const int skoff = (lane & 3) * 8;
  const int m0 = blockIdx.x * 128;

  f32x4 acc[2][2];
  #pragma unroll
  for (int m = 0; m < 2; ++m)
    #pragma unroll
    for (int n = 0; n < 2; ++n)
      #pragma unroll
      for (int r = 0; r < 4; ++r) acc[m][n][r] = 0.f;

  for (int k0 = 0; k0 < 2048; k0 += 32){
    int ks = k0 & 1023;
    #pragma unroll
    for (int r = 0; r < 2; ++r){
      int chunk = r * 4 + wave;
      int rr = chunk * 16 + srow;
      gload16(A + (size_t)(m0 + rr) * 1024 + ks + skoff, &tA[chunk * 512]);
    }
    if (wave < 2){
      int rr = wave * 16 + srow;
      gload16(Bt + (size_t)rr * 2048 + k0 + skoff, &tB[wave * 512]);
    }
    __syncthreads();
    short8 af[2], bfv[2];
    #pragma unroll
    for (int m = 0; m < 2; ++m)
      af[m] = *(const short8*)&tA[(wave * 32 + m * 16 + l15) * 32 + l4 * 8];
    #pragma unroll
    for (int n = 0; n < 2; ++n)
      bfv[n] = *(const short8*)&tB[(n * 16 + l15) * 32 + l4 * 8];
    #pragma unroll
    for (int m = 0; m < 2; ++m)
      #pragma unroll
      for (int n = 0; n < 2; ++n)
        acc[m][n] = __builtin_amdgcn_mfma_f32_16x16x32_bf16(af[m], bfv[n], acc[m][n], 0, 0, 0);
    __syncthreads();
  }
  #pragma unroll
  for (int n = 0; n < 2; ++n){
    int col = n * 16 + l15;
    #pragma unroll
    for (int m = 0; m < 2; ++m){
      int rowb = m0 + wave * 32 + m * 16 + l4 * 4;
      #pragma unroll
      for (int r = 0; r < 4; ++r)
        dtr[(size_t)(rowb + r) * 32 + col] = acc[m][n][r];
    }
  }
}

// ---------------- causal depthwise conv (k=4) + SiLU: time-iterating, 4ch/thread ----------------
__global__ __launch_bounds__(192)
void k_conv(const ushort_t* __restrict__ xbc, const float* __restrict__ conv_w,
            const float* __restrict__ conv_b, ushort_t* __restrict__ xh,
            float* __restrict__ bmat, float* __restrict__ c_last){
  const int c0 = (blockIdx.x * 192 + threadIdx.x) * 4;   // 3 * 768 = 2304 channels
  const int t0 = blockIdx.y * TCH;
  const int b  = blockIdx.z;
  const size_t rowbase = (size_t)b * 2048;

  float cw[4][4], cb[4];
  #pragma unroll
  for (int j = 0; j < 4; ++j){
    cb[j] = conv_b[c0 + j];
    #pragma unroll
    for (int k = 0; k < 4; ++k) cw[j][k] = conv_w[(c0 + j) * 4 + k];
  }
  float h[3][4];
  #pragma unroll
  for (int k = 0; k < 3; ++k){
    int tt = t0 - 3 + k;
    if (tt >= 0){
      short4v v = *(const short4v*)&xbc[(rowbase + tt) * 2304 + c0];
      #pragma unroll
      for (int j = 0; j < 4; ++j) h[k][j] = bf2f((ushort_t)v[j]);
    } else {
      #pragma unroll
      for (int j = 0; j < 4; ++j) h[k][j] = 0.f;
    }
  }
  for (int t = t0; t < t0 + TCH; ++t){
    short4v v = *(const short4v*)&xbc[(rowbase + t) * 2304 + c0];
    float outv[4];
    #pragma unroll
    for (int j = 0; j < 4; ++j){
      float x = bf2f((ushort_t)v[j]);
      float a = cb[j] + h[0][j] * cw[j][0] + h[1][j] * cw[j][1] + h[2][j] * cw[j][2] + x * cw[j][3];
      outv[j] = a / (1.f + __expf(-a));
      h[0][j] = h[1][j]; h[1][j] = h[2][j]; h[2][j] = x;
    }
    if (c0 < 2048){
      ushort4v o;
      #pragma unroll
      for (int j = 0; j < 4; ++j) o[j] = f2bf(outv[j]);
      *(ushort4v*)&xh[(rowbase + t) * 2048 + c0] = o;
    } else if (c0 < 2176){
      f32x4 o;
      #pragma unroll
      for (int j = 0; j < 4; ++j) o[j] = outv[j];
      *(f32x4*)&bmat[(rowbase + t) * 128 + (c0 - 2048)] = o;
    } else if (t == 2047){
      f32x4 o;
      #pragma unroll
      for (int j = 0; j < 4; ++j) o[j] = outv[j];
      *(f32x4*)&c_last[b * 128 + (c0 - 2176)] = o;
    }
  }
}

// ---------------- g[b,t] = B_t . C_last ----------------
__global__ void k_gdot(const float* __restrict__ bmat, const float* __restrict__ c_last,
                       float* __restrict__ g){
  int r = threadIdx.x >> 5, n = threadIdx.x & 31;
  int row = blockIdx.x * 8 + r;
  int b = row >> 11;
  const float* bp = bmat + (size_t)row * 128;
  const float* cp = c_last + b * 128;
  float acc = 0.f;
  #pragma unroll
  for (int j = 0; j < 4; ++j) acc += bp[n + 32 * j] * cp[n + 32 * j];
  for (int s = 16; s; s >>= 1) acc += __shfl_down(acc, s, 32);
  if (n == 0) g[row] = acc;
}

// ---------------- per-(b,h) suffix scan -> coeff[t] = exp(S_t)*dt_t*g_t ----------------
__global__ void k_coeff(const float* __restrict__ dt_raw, const float* __restrict__ dt_bias,
                        const float* __restrict__ A_log, const float* __restrict__ g,
                        float* __restrict__ coeffw){
  __shared__ float csum[256];
  int bh = blockIdx.x;             // b*32 + h
  int b = bh >> 5, h = bh & 31;
  float Ah = -__expf(A_log[h]);
  float bias = dt_bias[h];
  int tid = threadIdx.x;
  size_t base = (size_t)b * 2048;
  float d[8], dts[8];
  #pragma unroll
  for (int j = 0; j < 8; ++j){
    int t = tid * 8 + j;
    float x = dt_raw[(base + t) * 32 + h] + bias;
    float sp = (x > 20.f) ? x : log1pf(__expf(x));
    dts[j] = sp;
    d[j] = sp * Ah;
  }
  float cs = 0.f;
  #pragma unroll
  for (int j = 0; j < 8; ++j) cs += d[j];
  csum[tid] = cs;
  __syncthreads();
  float suf = 0.f;
  for (int j = tid + 1; j < 256; ++j) suf += csum[j];
  float S = suf, outv[8];
  for (int j = 7; j >= 0; --j){ outv[j] = S; S += d[j]; }
  #pragma unroll
  for (int j = 0; j < 8; ++j){
    int t = tid * 8 + j;
    coeffw[(size_t)bh * 2048 + t] = __expf(outv[j]) * dts[j] * g[base + t];
  }
}

// ---------------- y_last partials ----------------
__global__ void k_ysum_p(const float* __restrict__ coeffw, const ushort_t* __restrict__ xh,
                         float* __restrict__ ypart){
  __shared__ float red[256];
  int bh = blockIdx.x, ch = blockIdx.y;
  int b = bh >> 5, h = bh & 31;
  int p = threadIdx.x & 63, stripe = threadIdx.x >> 6;
  const float* cw = coeffw + (size_t)bh * 2048 + ch * 256;
  const ushort_t* xp = xh + ((size_t)b * 2048 + ch * 256) * 2048 + h * 64 + p;
  float acc = 0.f;
  for (int t = stripe; t < 256; t += 4)
    acc += cw[t] * bf2f(xp[(size_t)t * 2048]);
  red[threadIdx.x] = acc;
  __syncthreads();
  if (stripe == 0)
    ypart[((size_t)bh * 8 + ch) * 64 + p] = red[p] + red[p + 64] + red[p + 128] + red[p + 192];
}
__global__ void k_ysum_r(const float* __restrict__ ypart, const ushort_t* __restrict__ xh,
                         const float* __restrict__ Dp, float* __restrict__ yfin){
  int i = blockIdx.x * 256 + threadIdx.x;      // 16384
  int bh = i >> 6, p = i & 63;
  int b = bh >> 5, h = bh & 31;
  float v = 0.f;
  #pragma unroll
  for (int c = 0; c < 8; ++c) v += ypart[((size_t)bh * 8 + c) * 64 + p];
  v += Dp[h] * bf2f(xh[((size_t)b * 2048 + 2047) * 2048 + h * 64 + p]);
  yfin[b * 2048 + h * 64 + p] = v;
}

// ---------------- z_last: wave per column, all 8 batches ----------------
__global__ __launch_bounds__(64)
void k_zlast(const ushort_t* __restrict__ u16, const float* __restrict__ wzT,
             float* __restrict__ z_last){
  int col = blockIdx.x;          // 2048
  int l = threadIdx.x;           // 64
  float acc[8] = {0.f, 0.f, 0.f, 0.f, 0.f, 0.f, 0.f, 0.f};
  const float* wp = wzT + (size_t)col * 1024;
  #pragma unroll 4
  for (int i = 0; i < 16; ++i){
    int k = i * 64 + l;
    float w = wp[k];
    #pragma unroll
    for (int b = 0; b < 8; ++b)
      acc[b] += bf2f(u16[((size_t)b * 2048 + 2047) * 1024 + k]) * w;
  }
  #pragma unroll
  for (int b = 0; b < 8; ++b){
    float v = acc[b];
    for (int s = 32; s; s >>= 1) v += __shfl_down(v, s, 64);
    if (l == 0) z_last[b * 2048 + col] = v;
  }
}

// ---------------- gated RMSNorm ----------------
__global__ void k_norm(const float* __restrict__ yfin, const float* __restrict__ z_last,
                       const float* __restrict__ norm_w, float* __restrict__ yn){
  __shared__ float red[256];
  int b = blockIdx.x, tid = threadIdx.x;
  float vals[8], ss = 0.f;
  #pragma unroll
  for (int j = 0; j < 8; ++j){
    int c = tid + 256 * j;
    float z = z_last[b * 2048 + c];
    float yg = yfin[b * 2048 + c] * (z / (1.f + __expf(-z)));
    vals[j] = yg; ss += yg * yg;
  }
  red[tid] = ss; __syncthreads();
  for (int s = 128; s; s >>= 1){
    if (tid < s) red[tid] += red[tid + s];
    __syncthreads();
  }
  float scale = rsqrtf(red[0] / 2048.f + EPSV);
  #pragma unroll
  for (int j = 0; j < 8; ++j){
    int c = tid + 256 * j;
    yn[b * 2048 + c] = vals[j] * scale * norm_w[c];
  }
}

// ---------------- out projection: wave per column, all 8 batches ----------------
__global__ __launch_bounds__(64)
void k_outproj(const float* __restrict__ yn, const float* __restrict__ wot,
               float* __restrict__ o){
  int col = blockIdx.x;          // 1024
  int l = threadIdx.x;           // 64
  float acc[8] = {0.f, 0.f, 0.f, 0.f, 0.f, 0.f, 0.f, 0.f};
  const float* wp = wot + (size_t)col * 2048;
  #pragma unroll 4
  for (int i = 0; i < 32; ++i){
    int k = i * 64 + l;
    float w = wp[k];
    #pragma unroll
    for (int b = 0; b < 8; ++b)
      acc[b] += yn[b * 2048 + k] * w;
  }
  #pragma unroll
  for (int b = 0; b < 8; ++b){
    float v = acc[b];
    for (int s = 32; s; s >>= 1) v += __shfl_down(v, s, 64);
    if (l == 0) o[b * 1024 + col] = v;
  }
}

// ---------------- head: wave per output column ----------------
__global__ __launch_bounds__(64)
void k_head(const float* __restrict__ o, const float* __restrict__ wht,
            const float* __restrict__ b_head, float* __restrict__ out){
  int j = blockIdx.x;            // 64
  int l = threadIdx.x;           // 64
  float acc[8] = {0.f, 0.f, 0.f, 0.f, 0.f, 0.f, 0.f, 0.f};
  const float* wp = wht + (size_t)j * 1024;
  #pragma unroll 4
  for (int i = 0; i < 16; ++i){
    int k = i * 64 + l;
    float w = wp[k];
    #pragma unroll
    for (int b = 0; b < 8; ++b)
      acc[b] += o[b * 1024 + k] * w;
  }
  #pragma unroll
  for (int b = 0; b < 8; ++b){
    float v = acc[b];
    for (int s = 32; s; s >>= 1) v += __shfl_down(v, s, 64);
    if (l == 0) out[b * 64 + j] = acc[0] * 0.f + v + b_head[j];
  }
}

extern "C" void kernel_launch(void* const* d_in, const int* in_sizes, int n_in,
                              void* d_out, int out_size, void* d_ws, size_t ws_size,
                              hipStream_t stream){
  (void)in_sizes; (void)n_in; (void)out_size; (void)ws_size;
  const float* x       = (const float*)d_in[0];
  const float* w_proj  = (const float*)d_in[1];
  const float* b_proj  = (const float*)d_in[2];
  const float* w_in    = (const float*)d_in[3];
  const float* conv_w  = (const float*)d_in[4];
  const float* conv_b  = (const float*)d_in[5];
  const float* A_log   = (const float*)d_in[6];
  const float* dt_bias = (const float*)d_in[7];
  const float* Dp      = (const float*)d_in[8];
  const float* norm_w  = (const float*)d_in[9];
  const float* w_out   = (const float*)d_in[10];
  const float* w_head  = (const float*)d_in[11];
  const float* b_head  = (const float*)d_in[12];
  float* out = (float*)d_out;

  char* ws = (char*)d_ws;
  size_t off = 0;
  auto alloc = [&](size_t bytes)->char*{
    char* p = ws + off; off += (bytes + 255) & ~(size_t)255; return p;
  };
  ushort_t* xb    = (ushort_t*)alloc((size_t)M_ROWS * 64 * 2);
  ushort_t* w1t   = (ushort_t*)alloc((size_t)1024 * 64 * 2);
  ushort_t* w2t   = (ushort_t*)alloc((size_t)2304 * 1024 * 2);
  ushort_t* wdt   = (ushort_t*)alloc((size_t)32 * 2048 * 2);
  float*    wzT   = (float*)alloc((size_t)2048 * 1024 * 4);
  float*    wot   = (float*)alloc((size_t)1024 * 2048 * 4);
  float*    wht   = (float*)alloc((size_t)64 * 1024 * 4);
  ushort_t* u16   = (ushort_t*)alloc((size_t)M_ROWS * 1024 * 2);
  ushort_t* xbc   = (ushort_t*)alloc((size_t)M_ROWS * 2304 * 2);
  float*    dtr   = (float*)alloc((size_t)M_ROWS * 32 * 4);
  ushort_t* xh    = (ushort_t*)alloc((size_t)M_ROWS * 2048 * 2);
  float*    bmat  = (float*)alloc((size_t)M_ROWS * 128 * 4);
  float*    clast = (float*)alloc((size_t)8 * 128 * 4);
  float*    g     = (float*)alloc((size_t)M_ROWS * 4);
  float*    cfw   = (float*)alloc((size_t)256 * 2048 * 4);
  float*    ypart = (float*)alloc((size_t)256 * 8 * 64 * 4);
  float*    yfin  = (float*)alloc((size_t)8 * 2048 * 4);
  float*    zl    = (float*)alloc((size_t)8 * 2048 * 4);
  float*    yn    = (float*)alloc((size_t)8 * 2048 * 4);
  float*    ov    = (float*)alloc((size_t)8 * 1024 * 4);

  k_cvt_bf16<<<(M_ROWS * 64 + 255) / 256, 256, 0, stream>>>(x, xb, M_ROWS * 64);
  k_w1t<<<(65536 + 255) / 256, 256, 0, stream>>>(w_proj, w1t);
  dim3 gw2(36, 16);
  k_w2t<<<gw2, 256, 0, stream>>>(w_in, w2t);
  k_wdt<<<(32768 + 255) / 256, 256, 0, stream>>>(w_in, wdt);
  dim3 gtz(32, 16);   // wzT: Cn=2048, R=1024
  k_transf32<<<gtz, 256, 0, stream>>>(w_in, wzT, 1024, 4384, 0);
  dim3 gto(16, 32);   // wot: Cn=1024, R=2048
  k_transf32<<<gto, 256, 0, stream>>>(w_out, wot, 2048, 1024, 0);
  dim3 gth(1, 16);    // wht: Cn=64, R=1024
  k_transf32<<<gth, 256, 0, stream>>>(w_head, wht, 1024, 64, 0);

  k_gemm_bf16<<<(1024 / 128) * (M_ROWS / 128), 256, 0, stream>>>(xb, w1t, b_proj, u16, 64, 1024, 1024 / 128);
  k_gemm_bf16<<<(2304 / 128) * (M_ROWS / 128), 256, 0, stream>>>(u16, w2t, nullptr, xbc, 1024, 2304, 2304 / 128);

  k_dtg<<<M_ROWS / 128, 256, 0, stream>>>(u16, wdt, dtr);

  dim3 gc(3, L_SEQ / TCH, BATCH);
  k_conv<<<gc, 192, 0, stream>>>(xbc, conv_w, conv_b, xh, bmat, clast);

  k_gdot<<<M_ROWS / 8, 256, 0, stream>>>(bmat, clast, g);
  k_coeff<<<256, 256, 0, stream>>>(dtr, dt_bias, A_log, g, cfw);

  dim3 gy(256, 8);
  k_ysum_p<<<gy, 256, 0, stream>>>(cfw, xh, ypart);
  k_ysum_r<<<M_ROWS / 256, 256, 0, stream>>>(ypart, xh, Dp, yfin);

  k_zlast<<<2048, 64, 0, stream>>>(u16, wzT, zl);
  k_norm<<<8, 256, 0, stream>>>(yfin, zl, norm_w, yn);
  k_outproj<<<1024, 64, 0, stream>>>(yn, wot, ov);
  k_head<<<64, 64, 0, stream>>>(ov, wht, b_head, out);
}

// Round 4
// 269.644 us; speedup vs baseline: 2.8133x; 1.0404x over previous
//
#include <hip/hip_runtime.h>
#include <hip/hip_bf16.h>
#include <stdint.h>

typedef unsigned short ushort_t;
typedef __attribute__((ext_vector_type(8))) short short8;
typedef __attribute__((ext_vector_type(4))) short short4v;
typedef __attribute__((ext_vector_type(4))) unsigned short ushort4v;
typedef __attribute__((ext_vector_type(4))) float f32x4;

#define L_SEQ   2048
#define BATCH   8
#define M_ROWS  16384          // BATCH*L_SEQ
#define DMODEL  1024
#define DINNER  2048
#define DSTATE  128
#define NHEADS  32
#define HEADDIM 64
#define CONVDIM 2304
#define DINPROJ 4384
#define EPSV    1e-5f
#define TCH     64             // conv time-chunk

__device__ __forceinline__ float bf2f(ushort_t u){
  union { uint32_t i; float f; } v; v.i = ((uint32_t)u) << 16; return v.f;
}
__device__ __forceinline__ ushort_t f2bf(float f){
  union { float f; uint32_t i; } v; v.f = f;
  uint32_t r = v.i + 0x7fffu + ((v.i >> 16) & 1u);
  return (ushort_t)(r >> 16);
}

// ---------------- conversion / transpose kernels ----------------
__global__ void k_cvt_bf16(const float* __restrict__ src, ushort_t* __restrict__ dst, int n){
  int i = blockIdx.x * blockDim.x + threadIdx.x;
  if (i < n) dst[i] = f2bf(src[i]);
}
// w1t[j*64 + k] = w_proj[k*1024 + j]   (j<1024, k<64)
__global__ void k_w1t(const float* __restrict__ w, ushort_t* __restrict__ out){
  int i = blockIdx.x * blockDim.x + threadIdx.x;
  if (i < 64 * 1024){ int k = i >> 10, j = i & 1023; out[j * 64 + k] = f2bf(w[i]); }
}
// LDS-tiled transpose to bf16: w2t[j*1024 + k] = w_in[k*4384 + 2048 + j]
__global__ __launch_bounds__(256)
void k_w2t(const float* __restrict__ w_in, ushort_t* __restrict__ out){
  __shared__ float tile[64][65];
  int j0 = blockIdx.x * 64;          // 36 tiles
  int k0 = blockIdx.y * 64;          // 16 tiles
  int tx = threadIdx.x & 63, ty = threadIdx.x >> 6;
  #pragma unroll
  for (int i = 0; i < 16; ++i){
    int kk = ty * 16 + i;
    tile[kk][tx] = w_in[(size_t)(k0 + kk) * 4384 + 2048 + j0 + tx];
  }
  __syncthreads();
  #pragma unroll
  for (int i = 0; i < 16; ++i){
    int jj = ty * 16 + i;
    out[(size_t)(j0 + jj) * 1024 + k0 + tx] = f2bf(tile[tx][jj]);
  }
}
// generic fp32 LDS-tiled transpose: dst[j*R + k] = src[k*C + colOff + j]
__global__ __launch_bounds__(256)
void k_transf32(const float* __restrict__ src, float* __restrict__ dst,
                int R, int C, int colOff){
  __shared__ float tile[64][65];
  int j0 = blockIdx.x * 64;
  int k0 = blockIdx.y * 64;
  int tx = threadIdx.x & 63, ty = threadIdx.x >> 6;
  #pragma unroll
  for (int i = 0; i < 16; ++i){
    int kk = ty * 16 + i;
    tile[kk][tx] = src[(size_t)(k0 + kk) * C + colOff + j0 + tx];
  }
  __syncthreads();
  #pragma unroll
  for (int i = 0; i < 16; ++i){
    int jj = ty * 16 + i;
    dst[(size_t)(j0 + jj) * R + k0 + tx] = tile[tx][jj];
  }
}
// dt weights hi/lo split, transposed
__global__ void k_wdt(const float* __restrict__ w_in, ushort_t* __restrict__ wdt){
  int i = blockIdx.x * blockDim.x + threadIdx.x;
  if (i < 32 * 1024){
    int n = i >> 10, k = i & 1023;
    float w = w_in[(size_t)k * 4384 + 4352 + n];
    ushort_t hi = f2bf(w);
    float lo = w - bf2f(hi);
    wdt[n * 2048 + k] = hi;
    wdt[n * 2048 + 1024 + k] = f2bf(lo);
  }
}

// ---------------- async global->LDS ----------------
__device__ __forceinline__ void gload16(const void* g, void* l){
  __builtin_amdgcn_global_load_lds((const __attribute__((address_space(1))) void*)g,
                                   (__attribute__((address_space(3))) void*)l, 16, 0, 0);
}

// ---------------- phase fences for the 8-phase schedule ----------------
__device__ __forceinline__ void phase_enter(){
  __builtin_amdgcn_sched_barrier(0);
  asm volatile("" ::: "memory");
  __builtin_amdgcn_s_barrier();
  asm volatile("" ::: "memory");
  __builtin_amdgcn_sched_barrier(0);
  __builtin_amdgcn_s_setprio(1);
}
__device__ __forceinline__ void phase_exit(){
  __builtin_amdgcn_s_setprio(0);
  __builtin_amdgcn_sched_barrier(0);
  asm volatile("" ::: "memory");
  __builtin_amdgcn_s_barrier();
  asm volatile("" ::: "memory");
  __builtin_amdgcn_sched_barrier(0);
}
__device__ __forceinline__ void phase_exit_vm(){
  __builtin_amdgcn_s_setprio(0);
  __builtin_amdgcn_sched_barrier(0);
  asm volatile("s_waitcnt vmcnt(4)" ::: "memory");
  __builtin_amdgcn_s_barrier();
  asm volatile("" ::: "memory");
  __builtin_amdgcn_sched_barrier(0);
}

// ---------------- 256x256 8-phase bf16 GEMM (K=1024 fixed): C = A * Bt^T ----------------
// 8 waves (2M x 4N), BK=64, double-buffered 128KiB LDS, XOR-swizzled reads,
// pre-swizzled global_load_lds source, counted vmcnt(4) at tile boundaries.
__global__ __launch_bounds__(512, 1)
void k_gemm256(const ushort_t* __restrict__ A, const ushort_t* __restrict__ Bt,
               ushort_t* __restrict__ C, int N, int nbx){
  __shared__ ushort_t lds[65536];   // 2 buf x (A 16K + B 16K elems)
  const int tid = threadIdx.x;
  const int lane = tid & 63;
  const int wave = tid >> 6;
  const int wr = wave >> 2, wc = wave & 3;
  const int l15 = lane & 15, l4 = lane >> 4;

  const int nwg = gridDim.x, cpx = nwg >> 3;
  const int swz = ((int)blockIdx.x & 7) * cpx + ((int)blockIdx.x >> 3);
  const int m0 = (swz / nbx) * 256, n0 = (swz % nbx) * 256;

  // swizzle: element-in-row e -> e ^ ((row&7)<<3); involution, 16B-chunk aligned
  const int stage_eg = ((tid & 7) * 8) ^ (((tid >> 3) & 7) << 3);
  const int e0 = (l4 * 8) ^ ((l15 & 7) << 3);
  const int e1 = (32 + l4 * 8) ^ ((l15 & 7) << 3);
  const int aoff_base = wr * 8192 + l15 * 64;
  const int boff_base = 16384 + (wc >> 1) * 8192 + ((wc & 1) * 64 + l15) * 64;

  auto stage = [&](int t, int isB, int h, int dbuf){
    if (t < 16){
      const ushort_t* src = isB ? Bt : A;
      const int row0 = (isB ? n0 : m0) + h * 128 + (tid >> 3);
      const int dst = dbuf * 32768 + isB * 16384 + h * 8192 + tid * 8;
      gload16(src + (size_t)row0 * 1024 + t * 64 + stage_eg, &lds[dst]);
      gload16(src + (size_t)(row0 + 64) * 1024 + t * 64 + stage_eg, &lds[dst + 4096]);
    }
  };

  f32x4 acc[8][4];
  #pragma unroll
  for (int m = 0; m < 8; ++m)
    #pragma unroll
    for (int n = 0; n < 4; ++n)
      #pragma unroll
      for (int r = 0; r < 4; ++r) acc[m][n][r] = 0.f;

  // prologue: tile0 (B0,B1,A0,A1)->buf0 ; tile1 (B0,B1)->buf1
  stage(0, 1, 0, 0); stage(0, 1, 1, 0);
  stage(0, 0, 0, 0); stage(0, 0, 1, 0);
  stage(1, 1, 0, 1); stage(1, 1, 1, 1);
  asm volatile("s_waitcnt vmcnt(4)" ::: "memory");
  __builtin_amdgcn_s_barrier();
  asm volatile("" ::: "memory");

  short8 aF[4][2], bK[2][2], bF[2][2];

  for (int i = 0; i < 8; ++i){
    #pragma unroll
    for (int hh = 0; hh < 2; ++hh){
      const int bufo = hh * 32768;
      const int tA_ = (hh == 0) ? 2 * i + 1 : 2 * i + 2;
      const int dbA = (hh == 0) ? 1 : 0;
      const int tB_ = (hh == 0) ? 2 * i + 2 : 2 * i + 3;
      const int dbB = (hh == 0) ? 0 : 1;
      const int ao = bufo + aoff_base;
      const int bo = bufo + boff_base;
      // ---- ph1: read A m0-3 + B n0-1 ; stage A0 ----
      #pragma unroll
      for (int m = 0; m < 4; ++m){
        aF[m][0] = *(const short8*)&lds[ao + m * 1024 + e0];
        aF[m][1] = *(const short8*)&lds[ao + m * 1024 + e1];
      }
      #pragma unroll
      for (int n = 0; n < 2; ++n){
        bK[n][0] = *(const short8*)&lds[bo + n * 1024 + e0];
        bK[n][1] = *(const short8*)&lds[bo + n * 1024 + e1];
      }
      stage(tA_, 0, 0, dbA);
      phase_enter();
      #pragma unroll
      for (int m = 0; m < 4; ++m)
        #pragma unroll
        for (int n = 0; n < 2; ++n){
          acc[m][n] = __builtin_amdgcn_mfma_f32_16x16x32_bf16(aF[m][0], bK[n][0], acc[m][n], 0, 0, 0);
          acc[m][n] = __builtin_amdgcn_mfma_f32_16x16x32_bf16(aF[m][1], bK[n][1], acc[m][n], 0, 0, 0);
        }
      phase_exit();
      // ---- ph2: read B n2-3 ; stage A1 ----
      #pragma unroll
      for (int n = 0; n < 2; ++n){
        bF[n][0] = *(const short8*)&lds[bo + (n + 2) * 1024 + e0];
        bF[n][1] = *(const short8*)&lds[bo + (n + 2) * 1024 + e1];
      }
      stage(tA_, 0, 1, dbA);
      phase_enter();
      #pragma unroll
      for (int m = 0; m < 4; ++m)
        #pragma unroll
        for (int n = 0; n < 2; ++n){
          acc[m][n + 2] = __builtin_amdgcn_mfma_f32_16x16x32_bf16(aF[m][0], bF[n][0], acc[m][n + 2], 0, 0, 0);
          acc[m][n + 2] = __builtin_amdgcn_mfma_f32_16x16x32_bf16(aF[m][1], bF[n][1], acc[m][n + 2], 0, 0, 0);
        }
      phase_exit();
      // ---- ph3: read A m4-7 ; stage B0 ----
      #pragma unroll
      for (int m = 0; m < 4; ++m){
        aF[m][0] = *(const short8*)&lds[ao + (m + 4) * 1024 + e0];
        aF[m][1] = *(const short8*)&lds[ao + (m + 4) * 1024 + e1];
      }
      stage(tB_, 1, 0, dbB);
      phase_enter();
      #pragma unroll
      for (int m = 0; m < 4; ++m)
        #pragma unroll
        for (int n = 0; n < 2; ++n){
          acc[m + 4][n + 2] = __builtin_amdgcn_mfma_f32_16x16x32_bf16(aF[m][0], bF[n][0], acc[m + 4][n + 2], 0, 0, 0);
          acc[m + 4][n + 2] = __builtin_amdgcn_mfma_f32_16x16x32_bf16(aF[m][1], bF[n][1], acc[m + 4][n + 2], 0, 0, 0);
        }
      phase_exit();
      // ---- ph4: no reads ; stage B1 ; counted vm wait ----
      stage(tB_, 1, 1, dbB);
      phase_enter();
      #pragma unroll
      for (int m = 0; m < 4; ++m)
        #pragma unroll
        for (int n = 0; n < 2; ++n){
          acc[m + 4][n] = __builtin_amdgcn_mfma_f32_16x16x32_bf16(aF[m][0], bK[n][0], acc[m + 4][n], 0, 0, 0);
          acc[m + 4][n] = __builtin_amdgcn_mfma_f32_16x16x32_bf16(aF[m][1], bK[n][1], acc[m + 4][n], 0, 0, 0);
        }
      phase_exit_vm();
    }
  }

  #pragma unroll
  for (int m = 0; m < 8; ++m){
    const int row = m0 + wr * 128 + m * 16 + l4 * 4;
    #pragma unroll
    for (int n = 0; n < 4; ++n){
      const int col = n0 + wc * 64 + n * 16 + l15;
      #pragma unroll
      for (int r = 0; r < 4; ++r)
        C[(size_t)(row + r) * N + col] = f2bf(acc[m][n][r]);
    }
  }
}

// ---------------- 128^2 bf16 MFMA GEMM (GEMM1 + generic) ----------------
__global__ __launch_bounds__(256)
void k_gemm_bf16(const ushort_t* __restrict__ A, const ushort_t* __restrict__ Bt,
                 const float* __restrict__ bias, ushort_t* __restrict__ C,
                 int K, int N, int nbx){
  __shared__ ushort_t tA[128 * 32];
  __shared__ ushort_t tB[128 * 32];
  const int nwg = gridDim.x;
  const int cpx = nwg >> 3;
  const int bid = blockIdx.x;
  const int swz = (bid & 7) * cpx + (bid >> 3);
  const int m0 = (swz / nbx) * 128, n0 = (swz % nbx) * 128;

  const int tid  = threadIdx.x;
  const int wave = tid >> 6, lane = tid & 63;
  const int wr = wave >> 1, wc = wave & 1;
  const int l15 = lane & 15, l4 = lane >> 4;
  const int srow  = lane >> 2;
  const int skoff = (lane & 3) * 8;

  f32x4 acc[4][4];
  #pragma unroll
  for (int m = 0; m < 4; ++m)
    #pragma unroll
    for (int n = 0; n < 4; ++n)
      #pragma unroll
      for (int r = 0; r < 4; ++r) acc[m][n][r] = 0.f;

  for (int k0 = 0; k0 < K; k0 += 32){
    #pragma unroll
    for (int r = 0; r < 2; ++r){
      int chunk = r * 4 + wave;
      int rr = chunk * 16 + srow;
      gload16(A  + (size_t)(m0 + rr) * K + k0 + skoff, &tA[chunk * 512]);
      gload16(Bt + (size_t)(n0 + rr) * K + k0 + skoff, &tB[chunk * 512]);
    }
    __syncthreads();
    short8 af[4], bfv[4];
    #pragma unroll
    for (int m = 0; m < 4; ++m)
      af[m] = *(const short8*)&tA[(wr * 64 + m * 16 + l15) * 32 + l4 * 8];
    #pragma unroll
    for (int n = 0; n < 4; ++n)
      bfv[n] = *(const short8*)&tB[(wc * 64 + n * 16 + l15) * 32 + l4 * 8];
    #pragma unroll
    for (int m = 0; m < 4; ++m)
      #pragma unroll
      for (int n = 0; n < 4; ++n)
        acc[m][n] = __builtin_amdgcn_mfma_f32_16x16x32_bf16(af[m], bfv[n], acc[m][n], 0, 0, 0);
    __syncthreads();
  }
  #pragma unroll
  for (int n = 0; n < 4; ++n){
    int col = n0 + wc * 64 + n * 16 + l15;
    float bv = bias ? bias[col] : 0.f;
    #pragma unroll
    for (int m = 0; m < 4; ++m){
      int rowb = m0 + wr * 64 + m * 16 + l4 * 4;
      #pragma unroll
      for (int r = 0; r < 4; ++r)
        C[(size_t)(rowb + r) * N + col] = f2bf(acc[m][n][r] + bv);
    }
  }
}

// ---------------- dt GEMM (fp32 out) ----------------
__global__ __launch_bounds__(256)
void k_dtg(const ushort_t* __restrict__ A, const ushort_t* __restrict__ Bt,
           float* __restrict__ dtr){
  __shared__ ushort_t tA[128 * 32];
  __shared__ ushort_t tB[32 * 32];
  const int tid  = threadIdx.x;
  const int wave = tid >> 6, lane = tid & 63;
  const int l15 = lane & 15, l4 = lane >> 4;
  const int srow  = lane >> 2;
  const int skoff = (lane & 3) * 8;
  const int m0 = blockIdx.x * 128;

  f32x4 acc[2][2];
  #pragma unroll
  for (int m = 0; m < 2; ++m)
    #pragma unroll
    for (int n = 0; n < 2; ++n)
      #pragma unroll
      for (int r = 0; r < 4; ++r) acc[m][n][r] = 0.f;

  for (int k0 = 0; k0 < 2048; k0 += 32){
    int ks = k0 & 1023;
    #pragma unroll
    for (int r = 0; r < 2; ++r){
      int chunk = r * 4 + wave;
      int rr = chunk * 16 + srow;
      gload16(A + (size_t)(m0 + rr) * 1024 + ks + skoff, &tA[chunk * 512]);
    }
    if (wave < 2){
      int rr = wave * 16 + srow;
      gload16(Bt + (size_t)rr * 2048 + k0 + skoff, &tB[wave * 512]);
    }
    __syncthreads();
    short8 af[2], bfv[2];
    #pragma unroll
    for (int m = 0; m < 2; ++m)
      af[m] = *(const short8*)&tA[(wave * 32 + m * 16 + l15) * 32 + l4 * 8];
    #pragma unroll
    for (int n = 0; n < 2; ++n)
      bfv[n] = *(const short8*)&tB[(n * 16 + l15) * 32 + l4 * 8];
    #pragma unroll
    for (int m = 0; m < 2; ++m)
      #pragma unroll
      for (int n = 0; n < 2; ++n)
        acc[m][n] = __builtin_amdgcn_mfma_f32_16x16x32_bf16(af[m], bfv[n], acc[m][n], 0, 0, 0);
    __syncthreads();
  }
  #pragma unroll
  for (int n = 0; n < 2; ++n){
    int col = n * 16 + l15;
    #pragma unroll
    for (int m = 0; m < 2; ++m){
      int rowb = m0 + wave * 32 + m * 16 + l4 * 4;
      #pragma unroll
      for (int r = 0; r < 4; ++r)
        dtr[(size_t)(rowb + r) * 32 + col] = acc[m][n][r];
    }
  }
}

// ---------------- causal depthwise conv (k=4) + SiLU ----------------
__global__ __launch_bounds__(192)
void k_conv(const ushort_t* __restrict__ xbc, const float* __restrict__ conv_w,
            const float* __restrict__ conv_b, ushort_t* __restrict__ xh,
            float* __restrict__ bmat, float* __restrict__ c_last){
  const int c0 = (blockIdx.x * 192 + threadIdx.x) * 4;
  const int t0 = blockIdx.y * TCH;
  const int b  = blockIdx.z;
  const size_t rowbase = (size_t)b * 2048;

  float cw[4][4], cb[4];
  #pragma unroll
  for (int j = 0; j < 4; ++j){
    cb[j] = conv_b[c0 + j];
    #pragma unroll
    for (int k = 0; k < 4; ++k) cw[j][k] = conv_w[(c0 + j) * 4 + k];
  }
  float h[3][4];
  #pragma unroll
  for (int k = 0; k < 3; ++k){
    int tt = t0 - 3 + k;
    if (tt >= 0){
      short4v v = *(const short4v*)&xbc[(rowbase + tt) * 2304 + c0];
      #pragma unroll
      for (int j = 0; j < 4; ++j) h[k][j] = bf2f((ushort_t)v[j]);
    } else {
      #pragma unroll
      for (int j = 0; j < 4; ++j) h[k][j] = 0.f;
    }
  }
  for (int t = t0; t < t0 + TCH; ++t){
    short4v v = *(const short4v*)&xbc[(rowbase + t) * 2304 + c0];
    float outv[4];
    #pragma unroll
    for (int j = 0; j < 4; ++j){
      float x = bf2f((ushort_t)v[j]);
      float a = cb[j] + h[0][j] * cw[j][0] + h[1][j] * cw[j][1] + h[2][j] * cw[j][2] + x * cw[j][3];
      outv[j] = a / (1.f + __expf(-a));
      h[0][j] = h[1][j]; h[1][j] = h[2][j]; h[2][j] = x;
    }
    if (c0 < 2048){
      ushort4v o;
      #pragma unroll
      for (int j = 0; j < 4; ++j) o[j] = f2bf(outv[j]);
      *(ushort4v*)&xh[(rowbase + t) * 2048 + c0] = o;
    } else if (c0 < 2176){
      f32x4 o;
      #pragma unroll
      for (int j = 0; j < 4; ++j) o[j] = outv[j];
      *(f32x4*)&bmat[(rowbase + t) * 128 + (c0 - 2048)] = o;
    } else if (t == 2047){
      f32x4 o;
      #pragma unroll
      for (int j = 0; j < 4; ++j) o[j] = outv[j];
      *(f32x4*)&c_last[b * 128 + (c0 - 2176)] = o;
    }
  }
}

// ---------------- g[b,t] = B_t . C_last ----------------
__global__ void k_gdot(const float* __restrict__ bmat, const float* __restrict__ c_last,
                       float* __restrict__ g){
  int r = threadIdx.x >> 5, n = threadIdx.x & 31;
  int row = blockIdx.x * 8 + r;
  int b = row >> 11;
  const float* bp = bmat + (size_t)row * 128;
  const float* cp = c_last + b * 128;
  float acc = 0.f;
  #pragma unroll
  for (int j = 0; j < 4; ++j) acc += bp[n + 32 * j] * cp[n + 32 * j];
  for (int s = 16; s; s >>= 1) acc += __shfl_down(acc, s, 32);
  if (n == 0) g[row] = acc;
}

// ---------------- per-(b,h) suffix scan -> coeff ----------------
__global__ void k_coeff(const float* __restrict__ dt_raw, const float* __restrict__ dt_bias,
                        const float* __restrict__ A_log, const float* __restrict__ g,
                        float* __restrict__ coeffw){
  __shared__ float csum[256];
  int bh = blockIdx.x;
  int b = bh >> 5, h = bh & 31;
  float Ah = -__expf(A_log[h]);
  float bias = dt_bias[h];
  int tid = threadIdx.x;
  size_t base = (size_t)b * 2048;
  float d[8], dts[8];
  #pragma unroll
  for (int j = 0; j < 8; ++j){
    int t = tid * 8 + j;
    float x = dt_raw[(base + t) * 32 + h] + bias;
    float sp = (x > 20.f) ? x : log1pf(__expf(x));
    dts[j] = sp;
    d[j] = sp * Ah;
  }
  float cs = 0.f;
  #pragma unroll
  for (int j = 0; j < 8; ++j) cs += d[j];
  csum[tid] = cs;
  __syncthreads();
  float suf = 0.f;
  for (int j = tid + 1; j < 256; ++j) suf += csum[j];
  float S = suf, outv[8];
  for (int j = 7; j >= 0; --j){ outv[j] = S; S += d[j]; }
  #pragma unroll
  for (int j = 0; j < 8; ++j){
    int t = tid * 8 + j;
    coeffw[(size_t)bh * 2048 + t] = __expf(outv[j]) * dts[j] * g[base + t];
  }
}

// ---------------- y_last partials ----------------
__global__ void k_ysum_p(const float* __restrict__ coeffw, const ushort_t* __restrict__ xh,
                         float* __restrict__ ypart){
  __shared__ float red[256];
  int bh = blockIdx.x, ch = blockIdx.y;
  int b = bh >> 5, h = bh & 31;
  int p = threadIdx.x & 63, stripe = threadIdx.x >> 6;
  const float* cw = coeffw + (size_t)bh * 2048 + ch * 256;
  const ushort_t* xp = xh + ((size_t)b * 2048 + ch * 256) * 2048 + h * 64 + p;
  float acc = 0.f;
  for (int t = stripe; t < 256; t += 4)
    acc += cw[t] * bf2f(xp[(size_t)t * 2048]);
  red[threadIdx.x] = acc;
  __syncthreads();
  if (stripe == 0)
    ypart[((size_t)bh * 8 + ch) * 64 + p] = red[p] + red[p + 64] + red[p + 128] + red[p + 192];
}
__global__ void k_ysum_r(const float* __restrict__ ypart, const ushort_t* __restrict__ xh,
                         const float* __restrict__ Dp, float* __restrict__ yfin){
  int i = blockIdx.x * 256 + threadIdx.x;
  int bh = i >> 6, p = i & 63;
  int b = bh >> 5, h = bh & 31;
  float v = 0.f;
  #pragma unroll
  for (int c = 0; c < 8; ++c) v += ypart[((size_t)bh * 8 + c) * 64 + p];
  v += Dp[h] * bf2f(xh[((size_t)b * 2048 + 2047) * 2048 + h * 64 + p]);
  yfin[b * 2048 + h * 64 + p] = v;
}

// ---------------- z_last: wave per column ----------------
__global__ __launch_bounds__(64)
void k_zlast(const ushort_t* __restrict__ u16, const float* __restrict__ wzT,
             float* __restrict__ z_last){
  int col = blockIdx.x;
  int l = threadIdx.x;
  float acc[8] = {0.f, 0.f, 0.f, 0.f, 0.f, 0.f, 0.f, 0.f};
  const float* wp = wzT + (size_t)col * 1024;
  #pragma unroll 4
  for (int i = 0; i < 16; ++i){
    int k = i * 64 + l;
    float w = wp[k];
    #pragma unroll
    for (int b = 0; b < 8; ++b)
      acc[b] += bf2f(u16[((size_t)b * 2048 + 2047) * 1024 + k]) * w;
  }
  #pragma unroll
  for (int b = 0; b < 8; ++b){
    float v = acc[b];
    for (int s = 32; s; s >>= 1) v += __shfl_down(v, s, 64);
    if (l == 0) z_last[b * 2048 + col] = v;
  }
}

// ---------------- gated RMSNorm ----------------
__global__ void k_norm(const float* __restrict__ yfin, const float* __restrict__ z_last,
                       const float* __restrict__ norm_w, float* __restrict__ yn){
  __shared__ float red[256];
  int b = blockIdx.x, tid = threadIdx.x;
  float vals[8], ss = 0.f;
  #pragma unroll
  for (int j = 0; j < 8; ++j){
    int c = tid + 256 * j;
    float z = z_last[b * 2048 + c];
    float yg = yfin[b * 2048 + c] * (z / (1.f + __expf(-z)));
    vals[j] = yg; ss += yg * yg;
  }
  red[tid] = ss; __syncthreads();
  for (int s = 128; s; s >>= 1){
    if (tid < s) red[tid] += red[tid + s];
    __syncthreads();
  }
  float scale = rsqrtf(red[0] / 2048.f + EPSV);
  #pragma unroll
  for (int j = 0; j < 8; ++j){
    int c = tid + 256 * j;
    yn[b * 2048 + c] = vals[j] * scale * norm_w[c];
  }
}

// ---------------- out projection: wave per column ----------------
__global__ __launch_bounds__(64)
void k_outproj(const float* __restrict__ yn, const float* __restrict__ wot,
               float* __restrict__ o){
  int col = blockIdx.x;
  int l = threadIdx.x;
  float acc[8] = {0.f, 0.f, 0.f, 0.f, 0.f, 0.f, 0.f, 0.f};
  const float* wp = wot + (size_t)col * 2048;
  #pragma unroll 4
  for (int i = 0; i < 32; ++i){
    int k = i * 64 + l;
    float w = wp[k];
    #pragma unroll
    for (int b = 0; b < 8; ++b)
      acc[b] += yn[b * 2048 + k] * w;
  }
  #pragma unroll
  for (int b = 0; b < 8; ++b){
    float v = acc[b];
    for (int s = 32; s; s >>= 1) v += __shfl_down(v, s, 64);
    if (l == 0) o[b * 1024 + col] = v;
  }
}

// ---------------- head: wave per output column ----------------
__global__ __launch_bounds__(64)
void k_head(const float* __restrict__ o, const float* __restrict__ wht,
            const float* __restrict__ b_head, float* __restrict__ out){
  int j = blockIdx.x;
  int l = threadIdx.x;
  float acc[8] = {0.f, 0.f, 0.f, 0.f, 0.f, 0.f, 0.f, 0.f};
  const float* wp = wht + (size_t)j * 1024;
  #pragma unroll 4
  for (int i = 0; i < 16; ++i){
    int k = i * 64 + l;
    float w = wp[k];
    #pragma unroll
    for (int b = 0; b < 8; ++b)
      acc[b] += o[b * 1024 + k] * w;
  }
  #pragma unroll
  for (int b = 0; b < 8; ++b){
    float v = acc[b];
    for (int s = 32; s; s >>= 1) v += __shfl_down(v, s, 64);
    if (l == 0) out[b * 64 + j] = v + b_head[j];
  }
}

extern "C" void kernel_launch(void* const* d_in, const int* in_sizes, int n_in,
                              void* d_out, int out_size, void* d_ws, size_t ws_size,
                              hipStream_t stream){
  (void)in_sizes; (void)n_in; (void)out_size; (void)ws_size;
  const float* x       = (const float*)d_in[0];
  const float* w_proj  = (const float*)d_in[1];
  const float* b_proj  = (const float*)d_in[2];
  const float* w_in    = (const float*)d_in[3];
  const float* conv_w  = (const float*)d_in[4];
  const float* conv_b  = (const float*)d_in[5];
  const float* A_log   = (const float*)d_in[6];
  const float* dt_bias = (const float*)d_in[7];
  const float* Dp      = (const float*)d_in[8];
  const float* norm_w  = (const float*)d_in[9];
  const float* w_out   = (const float*)d_in[10];
  const float* w_head  = (const float*)d_in[11];
  const float* b_head  = (const float*)d_in[12];
  float* out = (float*)d_out;

  char* ws = (char*)d_ws;
  size_t off = 0;
  auto alloc = [&](size_t bytes)->char*{
    char* p = ws + off; off += (bytes + 255) & ~(size_t)255; return p;
  };
  ushort_t* xb    = (ushort_t*)alloc((size_t)M_ROWS * 64 * 2);
  ushort_t* w1t   = (ushort_t*)alloc((size_t)1024 * 64 * 2);
  ushort_t* w2t   = (ushort_t*)alloc((size_t)2304 * 1024 * 2);
  ushort_t* wdt   = (ushort_t*)alloc((size_t)32 * 2048 * 2);
  float*    wzT   = (float*)alloc((size_t)2048 * 1024 * 4);
  float*    wot   = (float*)alloc((size_t)1024 * 2048 * 4);
  float*    wht   = (float*)alloc((size_t)64 * 1024 * 4);
  ushort_t* u16   = (ushort_t*)alloc((size_t)M_ROWS * 1024 * 2);
  ushort_t* xbc   = (ushort_t*)alloc((size_t)M_ROWS * 2304 * 2);
  float*    dtr   = (float*)alloc((size_t)M_ROWS * 32 * 4);
  ushort_t* xh    = (ushort_t*)alloc((size_t)M_ROWS * 2048 * 2);
  float*    bmat  = (float*)alloc((size_t)M_ROWS * 128 * 4);
  float*    clast = (float*)alloc((size_t)8 * 128 * 4);
  float*    g     = (float*)alloc((size_t)M_ROWS * 4);
  float*    cfw   = (float*)alloc((size_t)256 * 2048 * 4);
  float*    ypart = (float*)alloc((size_t)256 * 8 * 64 * 4);
  float*    yfin  = (float*)alloc((size_t)8 * 2048 * 4);
  float*    zl    = (float*)alloc((size_t)8 * 2048 * 4);
  float*    yn    = (float*)alloc((size_t)8 * 2048 * 4);
  float*    ov    = (float*)alloc((size_t)8 * 1024 * 4);

  k_cvt_bf16<<<(M_ROWS * 64 + 255) / 256, 256, 0, stream>>>(x, xb, M_ROWS * 64);
  k_w1t<<<(65536 + 255) / 256, 256, 0, stream>>>(w_proj, w1t);
  dim3 gw2(36, 16);
  k_w2t<<<gw2, 256, 0, stream>>>(w_in, w2t);
  k_wdt<<<(32768 + 255) / 256, 256, 0, stream>>>(w_in, wdt);
  dim3 gtz(32, 16);
  k_transf32<<<gtz, 256, 0, stream>>>(w_in, wzT, 1024, 4384, 0);
  dim3 gto(16, 32);
  k_transf32<<<gto, 256, 0, stream>>>(w_out, wot, 2048, 1024, 0);
  dim3 gth(1, 16);
  k_transf32<<<gth, 256, 0, stream>>>(w_head, wht, 1024, 64, 0);

  k_gemm_bf16<<<(1024 / 128) * (M_ROWS / 128), 256, 0, stream>>>(xb, w1t, b_proj, u16, 64, 1024, 1024 / 128);

  // GEMM2: 256^2 8-phase pipelined kernel, grid 64 x 9 = 576 (%8 == 0)
  k_gemm256<<<(M_ROWS / 256) * (2304 / 256), 512, 0, stream>>>(u16, w2t, xbc, 2304, 2304 / 256);

  k_dtg<<<M_ROWS / 128, 256, 0, stream>>>(u16, wdt, dtr);

  dim3 gc(3, L_SEQ / TCH, BATCH);
  k_conv<<<gc, 192, 0, stream>>>(xbc, conv_w, conv_b, xh, bmat, clast);

  k_gdot<<<M_ROWS / 8, 256, 0, stream>>>(bmat, clast, g);
  k_coeff<<<256, 256, 0, stream>>>(dtr, dt_bias, A_log, g, cfw);

  dim3 gy(256, 8);
  k_ysum_p<<<gy, 256, 0, stream>>>(cfw, xh, ypart);
  k_ysum_r<<<M_ROWS / 256, 256, 0, stream>>>(ypart, xh, Dp, yfin);

  k_zlast<<<2048, 64, 0, stream>>>(u16, wzT, zl);
  k_norm<<<8, 256, 0, stream>>>(yfin, zl, norm_w, yn);
  k_outproj<<<1024, 64, 0, stream>>>(yn, wot, ov);
  k_head<<<64, 64, 0, stream>>>(ov, wht, b_head, out);
}

// Round 5
// 267.920 us; speedup vs baseline: 2.8314x; 1.0064x over previous
//
#include <hip/hip_runtime.h>
#include <hip/hip_bf16.h>
#include <stdint.h>

typedef unsigned short ushort_t;
typedef __attribute__((ext_vector_type(8))) short short8;
typedef __attribute__((ext_vector_type(4))) short short4v;
typedef __attribute__((ext_vector_type(4))) unsigned short ushort4v;
typedef __attribute__((ext_vector_type(4))) float f32x4;

#define L_SEQ   2048
#define BATCH   8
#define M_ROWS  16384          // BATCH*L_SEQ
#define DMODEL  1024
#define DINNER  2048
#define DSTATE  128
#define NHEADS  32
#define HEADDIM 64
#define CONVDIM 2304
#define DINPROJ 4384
#define EPSV    1e-5f
#define TCH     32             // conv time-chunk

__device__ __forceinline__ float bf2f(ushort_t u){
  union { uint32_t i; float f; } v; v.i = ((uint32_t)u) << 16; return v.f;
}
__device__ __forceinline__ ushort_t f2bf(float f){
  union { float f; uint32_t i; } v; v.f = f;
  uint32_t r = v.i + 0x7fffu + ((v.i >> 16) & 1u);
  return (ushort_t)(r >> 16);
}

// ---------------- conversion / transpose kernels ----------------
__global__ void k_cvt_bf16(const float* __restrict__ src, ushort_t* __restrict__ dst, int n){
  int i = blockIdx.x * blockDim.x + threadIdx.x;
  if (i < n) dst[i] = f2bf(src[i]);
}
__global__ void k_w1t(const float* __restrict__ w, ushort_t* __restrict__ out){
  int i = blockIdx.x * blockDim.x + threadIdx.x;
  if (i < 64 * 1024){ int k = i >> 10, j = i & 1023; out[j * 64 + k] = f2bf(w[i]); }
}
__global__ __launch_bounds__(256)
void k_w2t(const float* __restrict__ w_in, ushort_t* __restrict__ out){
  __shared__ float tile[64][65];
  int j0 = blockIdx.x * 64;
  int k0 = blockIdx.y * 64;
  int tx = threadIdx.x & 63, ty = threadIdx.x >> 6;
  #pragma unroll
  for (int i = 0; i < 16; ++i){
    int kk = ty * 16 + i;
    tile[kk][tx] = w_in[(size_t)(k0 + kk) * 4384 + 2048 + j0 + tx];
  }
  __syncthreads();
  #pragma unroll
  for (int i = 0; i < 16; ++i){
    int jj = ty * 16 + i;
    out[(size_t)(j0 + jj) * 1024 + k0 + tx] = f2bf(tile[tx][jj]);
  }
}
__global__ __launch_bounds__(256)
void k_transf32(const float* __restrict__ src, float* __restrict__ dst,
                int R, int C, int colOff){
  __shared__ float tile[64][65];
  int j0 = blockIdx.x * 64;
  int k0 = blockIdx.y * 64;
  int tx = threadIdx.x & 63, ty = threadIdx.x >> 6;
  #pragma unroll
  for (int i = 0; i < 16; ++i){
    int kk = ty * 16 + i;
    tile[kk][tx] = src[(size_t)(k0 + kk) * C + colOff + j0 + tx];
  }
  __syncthreads();
  #pragma unroll
  for (int i = 0; i < 16; ++i){
    int jj = ty * 16 + i;
    dst[(size_t)(j0 + jj) * R + k0 + tx] = tile[tx][jj];
  }
}
__global__ void k_wdt(const float* __restrict__ w_in, ushort_t* __restrict__ wdt){
  int i = blockIdx.x * blockDim.x + threadIdx.x;
  if (i < 32 * 1024){
    int n = i >> 10, k = i & 1023;
    float w = w_in[(size_t)k * 4384 + 4352 + n];
    ushort_t hi = f2bf(w);
    float lo = w - bf2f(hi);
    wdt[n * 2048 + k] = hi;
    wdt[n * 2048 + 1024 + k] = f2bf(lo);
  }
}

// ---------------- async global->LDS ----------------
__device__ __forceinline__ void gload16(const void* g, void* l){
  __builtin_amdgcn_global_load_lds((const __attribute__((address_space(1))) void*)g,
                                   (__attribute__((address_space(3))) void*)l, 16, 0, 0);
}
__device__ __forceinline__ void BAR(){
  asm volatile("" ::: "memory");
  __builtin_amdgcn_s_barrier();
  asm volatile("" ::: "memory");
}

// ---------------- 256x256 8-phase bf16 GEMM (K=1024): C = A * Bt^T ----------------
// 8 waves (2M x 4N), BK=64, 128KiB dbuf LDS, XOR-swizzled, balanced read slots
// {Alo:8, Bhi:4, Ahi:8, BloNext:4}, vmcnt(6)@P3-exit, vmcnt(4)@P4-exit.
__global__ __launch_bounds__(512, 1)
void k_gemm256(const ushort_t* __restrict__ A, const ushort_t* __restrict__ Bt,
               ushort_t* __restrict__ C, int N, int nbx){
  __shared__ ushort_t lds[65536];
  const int tid = threadIdx.x;
  const int lane = tid & 63;
  const int wave = tid >> 6;
  const int wr = wave >> 2, wc = wave & 3;
  const int l15 = lane & 15, l4 = lane >> 4;

  const int nwg = gridDim.x, cpx = nwg >> 3;
  const int swz = ((int)blockIdx.x & 7) * cpx + ((int)blockIdx.x >> 3);
  const int m0 = (swz / nbx) * 256, n0 = (swz % nbx) * 256;

  const int stage_eg = ((tid & 7) * 8) ^ (((tid >> 3) & 7) << 3);
  const int e0 = (l4 * 8) ^ ((l15 & 7) << 3);
  const int e1 = (32 + l4 * 8) ^ ((l15 & 7) << 3);
  const int aoff_base = wr * 8192 + l15 * 64;
  const int boff_base = 16384 + (wc >> 1) * 8192 + ((wc & 1) * 64 + l15) * 64;

  auto stage = [&](int t, int isB, int h, int dbuf){
    if (t < 16){
      const ushort_t* src = isB ? Bt : A;
      const int row0 = (isB ? n0 : m0) + h * 128 + (tid >> 3);
      const int dst = dbuf * 32768 + isB * 16384 + h * 8192 + tid * 8;
      gload16(src + (size_t)row0 * 1024 + t * 64 + stage_eg, &lds[dst]);
      gload16(src + (size_t)(row0 + 64) * 1024 + t * 64 + stage_eg, &lds[dst + 4096]);
    }
  };

  f32x4 acc[8][4];
  #pragma unroll
  for (int m = 0; m < 8; ++m)
    #pragma unroll
    for (int n = 0; n < 4; ++n)
      #pragma unroll
      for (int r = 0; r < 4; ++r) acc[m][n][r] = 0.f;

  // prologue: B(0)->buf0, A(0)->buf0, B(1)->buf1 ; then read Blo(0)
  stage(0, 1, 0, 0); stage(0, 1, 1, 0);
  stage(0, 0, 0, 0); stage(0, 0, 1, 0);
  stage(1, 1, 0, 1); stage(1, 1, 1, 1);
  asm volatile("s_waitcnt vmcnt(4)" ::: "memory");
  BAR();

  short8 aLo[4][2], aHi[4][2], bHi[2][2], bLoA[2][2], bLoB[2][2];
  #pragma unroll
  for (int n = 0; n < 2; ++n){
    bLoA[n][0] = *(const short8*)&lds[boff_base + n * 1024 + e0];
    bLoA[n][1] = *(const short8*)&lds[boff_base + n * 1024 + e1];
  }

#define TILE4(BUFO, OTH, TA, DBA, TB, DBB, BLO_CUR, BLO_NXT)                              \
  {                                                                                        \
    const int ao = (BUFO) + aoff_base;                                                     \
    const int bo = (BUFO) + boff_base;                                                     \
    const int boN = (OTH) + boff_base;                                                     \
    /* P1: read Alo(T); stage A0(T+1) */                                                   \
    _Pragma("unroll")                                                                      \
    for (int m = 0; m < 4; ++m){                                                           \
      aLo[m][0] = *(const short8*)&lds[ao + m * 1024 + e0];                                \
      aLo[m][1] = *(const short8*)&lds[ao + m * 1024 + e1];                                \
    }                                                                                      \
    stage((TA), 0, 0, (DBA));                                                              \
    BAR();                                                                                 \
    __builtin_amdgcn_s_setprio(1);                                                         \
    _Pragma("unroll")                                                                      \
    for (int m = 0; m < 4; ++m)                                                            \
      _Pragma("unroll")                                                                    \
      for (int n = 0; n < 2; ++n){                                                         \
        acc[m][n] = __builtin_amdgcn_mfma_f32_16x16x32_bf16(aLo[m][0], BLO_CUR[n][0], acc[m][n], 0, 0, 0); \
        acc[m][n] = __builtin_amdgcn_mfma_f32_16x16x32_bf16(aLo[m][1], BLO_CUR[n][1], acc[m][n], 0, 0, 0); \
      }                                                                                    \
    __builtin_amdgcn_s_setprio(0);                                                         \
    BAR();                                                                                 \
    /* P2: read Bhi(T); stage A1(T+1) */                                                   \
    _Pragma("unroll")                                                                      \
    for (int n = 0; n < 2; ++n){                                                           \
      bHi[n][0] = *(const short8*)&lds[bo + (n + 2) * 1024 + e0];                          \
      bHi[n][1] = *(const short8*)&lds[bo + (n + 2) * 1024 + e1];                          \
    }                                                                                      \
    stage((TA), 0, 1, (DBA));                                                              \
    BAR();                                                                                 \
    __builtin_amdgcn_s_setprio(1);                                                         \
    _Pragma("unroll")                                                                      \
    for (int m = 0; m < 4; ++m)                                                            \
      _Pragma("unroll")                                                                    \
      for (int n = 0; n < 2; ++n){                                                         \
        acc[m][n + 2] = __builtin_amdgcn_mfma_f32_16x16x32_bf16(aLo[m][0], bHi[n][0], acc[m][n + 2], 0, 0, 0); \
        acc[m][n + 2] = __builtin_amdgcn_mfma_f32_16x16x32_bf16(aLo[m][1], bHi[n][1], acc[m][n + 2], 0, 0, 0); \
      }                                                                                    \
    __builtin_amdgcn_s_setprio(0);                                                         \
    BAR();                                                                                 \
    /* P3: read Ahi(T); stage B0(T+2); vmcnt(6) */                                         \
    _Pragma("unroll")                                                                      \
    for (int m = 0; m < 4; ++m){                                                           \
      aHi[m][0] = *(const short8*)&lds[ao + (m + 4) * 1024 + e0];                          \
      aHi[m][1] = *(const short8*)&lds[ao + (m + 4) * 1024 + e1];                          \
    }                                                                                      \
    stage((TB), 1, 0, (DBB));                                                              \
    BAR();                                                                                 \
    __builtin_amdgcn_s_setprio(1);                                                         \
    _Pragma("unroll")                                                                      \
    for (int m = 0; m < 4; ++m)                                                            \
      _Pragma("unroll")                                                                    \
      for (int n = 0; n < 2; ++n){                                                         \
        acc[m + 4][n + 2] = __builtin_amdgcn_mfma_f32_16x16x32_bf16(aHi[m][0], bHi[n][0], acc[m + 4][n + 2], 0, 0, 0); \
        acc[m + 4][n + 2] = __builtin_amdgcn_mfma_f32_16x16x32_bf16(aHi[m][1], bHi[n][1], acc[m + 4][n + 2], 0, 0, 0); \
      }                                                                                    \
    __builtin_amdgcn_s_setprio(0);                                                         \
    asm volatile("s_waitcnt vmcnt(6)" ::: "memory");                                       \
    BAR();                                                                                 \
    /* P4: read Blo(T+1) from other buf; stage B1(T+2); vmcnt(4) */                        \
    _Pragma("unroll")                                                                      \
    for (int n = 0; n < 2; ++n){                                                           \
      BLO_NXT[n][0] = *(const short8*)&lds[boN + n * 1024 + e0];                           \
      BLO_NXT[n][1] = *(const short8*)&lds[boN + n * 1024 + e1];                           \
    }                                                                                      \
    stage((TB), 1, 1, (DBB));                                                              \
    BAR();                                                                                 \
    __builtin_amdgcn_s_setprio(1);                                                         \
    _Pragma("unroll")                                                                      \
    for (int m = 0; m < 4; ++m)                                                            \
      _Pragma("unroll")                                                                    \
      for (int n = 0; n < 2; ++n){                                                         \
        acc[m + 4][n] = __builtin_amdgcn_mfma_f32_16x16x32_bf16(aHi[m][0], BLO_CUR[n][0], acc[m + 4][n], 0, 0, 0); \
        acc[m + 4][n] = __builtin_amdgcn_mfma_f32_16x16x32_bf16(aHi[m][1], BLO_CUR[n][1], acc[m + 4][n], 0, 0, 0); \
      }                                                                                    \
    __builtin_amdgcn_s_setprio(0);                                                         \
    asm volatile("s_waitcnt vmcnt(4)" ::: "memory");                                       \
    BAR();                                                                                 \
  }

  for (int i = 0; i < 8; ++i){
    // tile T=2i   (buf0): stage A(T+1)->buf1, B(T+2)->buf0; BloCur=bLoA, next->bLoB
    TILE4(0, 32768, 2 * i + 1, 1, 2 * i + 2, 0, bLoA, bLoB)
    // tile T=2i+1 (buf1): stage A(T+2)->buf0, B(T+3)->buf1; BloCur=bLoB, next->bLoA
    TILE4(32768, 0, 2 * i + 2, 0, 2 * i + 3, 1, bLoB, bLoA)
  }
#undef TILE4

  #pragma unroll
  for (int m = 0; m < 8; ++m){
    const int row = m0 + wr * 128 + m * 16 + l4 * 4;
    #pragma unroll
    for (int n = 0; n < 4; ++n){
      const int col = n0 + wc * 64 + n * 16 + l15;
      #pragma unroll
      for (int r = 0; r < 4; ++r)
        C[(size_t)(row + r) * N + col] = f2bf(acc[m][n][r]);
    }
  }
}

// ---------------- 128^2 bf16 MFMA GEMM (GEMM1) ----------------
__global__ __launch_bounds__(256)
void k_gemm_bf16(const ushort_t* __restrict__ A, const ushort_t* __restrict__ Bt,
                 const float* __restrict__ bias, ushort_t* __restrict__ C,
                 int K, int N, int nbx){
  __shared__ ushort_t tA[128 * 32];
  __shared__ ushort_t tB[128 * 32];
  const int nwg = gridDim.x;
  const int cpx = nwg >> 3;
  const int bid = blockIdx.x;
  const int swz = (bid & 7) * cpx + (bid >> 3);
  const int m0 = (swz / nbx) * 128, n0 = (swz % nbx) * 128;

  const int tid  = threadIdx.x;
  const int wave = tid >> 6, lane = tid & 63;
  const int wr = wave >> 1, wc = wave & 1;
  const int l15 = lane & 15, l4 = lane >> 4;
  const int srow  = lane >> 2;
  const int skoff = (lane & 3) * 8;

  f32x4 acc[4][4];
  #pragma unroll
  for (int m = 0; m < 4; ++m)
    #pragma unroll
    for (int n = 0; n < 4; ++n)
      #pragma unroll
      for (int r = 0; r < 4; ++r) acc[m][n][r] = 0.f;

  for (int k0 = 0; k0 < K; k0 += 32){
    #pragma unroll
    for (int r = 0; r < 2; ++r){
      int chunk = r * 4 + wave;
      int rr = chunk * 16 + srow;
      gload16(A  + (size_t)(m0 + rr) * K + k0 + skoff, &tA[chunk * 512]);
      gload16(Bt + (size_t)(n0 + rr) * K + k0 + skoff, &tB[chunk * 512]);
    }
    __syncthreads();
    short8 af[4], bfv[4];
    #pragma unroll
    for (int m = 0; m < 4; ++m)
      af[m] = *(const short8*)&tA[(wr * 64 + m * 16 + l15) * 32 + l4 * 8];
    #pragma unroll
    for (int n = 0; n < 4; ++n)
      bfv[n] = *(const short8*)&tB[(wc * 64 + n * 16 + l15) * 32 + l4 * 8];
    #pragma unroll
    for (int m = 0; m < 4; ++m)
      #pragma unroll
      for (int n = 0; n < 4; ++n)
        acc[m][n] = __builtin_amdgcn_mfma_f32_16x16x32_bf16(af[m], bfv[n], acc[m][n], 0, 0, 0);
    __syncthreads();
  }
  #pragma unroll
  for (int n = 0; n < 4; ++n){
    int col = n0 + wc * 64 + n * 16 + l15;
    float bv = bias ? bias[col] : 0.f;
    #pragma unroll
    for (int m = 0; m < 4; ++m){
      int rowb = m0 + wr * 64 + m * 16 + l4 * 4;
      #pragma unroll
      for (int r = 0; r < 4; ++r)
        C[(size_t)(rowb + r) * N + col] = f2bf(acc[m][n][r] + bv);
    }
  }
}

// ---------------- dt GEMM (fp32 out, single A pass, dual-B accumulate) ----------------
__global__ __launch_bounds__(256)
void k_dtg(const ushort_t* __restrict__ A, const ushort_t* __restrict__ Bt,
           float* __restrict__ dtr){
  __shared__ ushort_t tA[128 * 32];
  __shared__ ushort_t tBh[32 * 32];
  __shared__ ushort_t tBl[32 * 32];
  const int tid  = threadIdx.x;
  const int wave = tid >> 6, lane = tid & 63;
  const int l15 = lane & 15, l4 = lane >> 4;
  const int srow  = lane >> 2;
  const int skoff = (lane & 3) * 8;
  const int m0 = blockIdx.x * 128;

  f32x4 acc[2][2];
  #pragma unroll
  for (int m = 0; m < 2; ++m)
    #pragma unroll
    for (int n = 0; n < 2; ++n)
      #pragma unroll
      for (int r = 0; r < 4; ++r) acc[m][n][r] = 0.f;

  for (int k0 = 0; k0 < 1024; k0 += 32){
    #pragma unroll
    for (int r = 0; r < 2; ++r){
      int chunk = r * 4 + wave;
      int rr = chunk * 16 + srow;
      gload16(A + (size_t)(m0 + rr) * 1024 + k0 + skoff, &tA[chunk * 512]);
    }
    if (wave < 2){
      int rr = wave * 16 + srow;
      gload16(Bt + (size_t)rr * 2048 + k0 + skoff, &tBh[wave * 512]);
    } else if (wave < 4){
      int rr = (wave - 2) * 16 + srow;
      gload16(Bt + (size_t)rr * 2048 + 1024 + k0 + skoff, &tBl[(wave - 2) * 512]);
    }
    __syncthreads();
    short8 af[2], bh[2], bl[2];
    #pragma unroll
    for (int m = 0; m < 2; ++m)
      af[m] = *(const short8*)&tA[(wave * 32 + m * 16 + l15) * 32 + l4 * 8];
    #pragma unroll
    for (int n = 0; n < 2; ++n){
      bh[n] = *(const short8*)&tBh[(n * 16 + l15) * 32 + l4 * 8];
      bl[n] = *(const short8*)&tBl[(n * 16 + l15) * 32 + l4 * 8];
    }
    #pragma unroll
    for (int m = 0; m < 2; ++m)
      #pragma unroll
      for (int n = 0; n < 2; ++n){
        acc[m][n] = __builtin_amdgcn_mfma_f32_16x16x32_bf16(af[m], bh[n], acc[m][n], 0, 0, 0);
        acc[m][n] = __builtin_amdgcn_mfma_f32_16x16x32_bf16(af[m], bl[n], acc[m][n], 0, 0, 0);
      }
    __syncthreads();
  }
  #pragma unroll
  for (int n = 0; n < 2; ++n){
    int col = n * 16 + l15;
    #pragma unroll
    for (int m = 0; m < 2; ++m){
      int rowb = m0 + wave * 32 + m * 16 + l4 * 4;
      #pragma unroll
      for (int r = 0; r < 4; ++r)
        dtr[(size_t)(rowb + r) * 32 + col] = acc[m][n][r];
    }
  }
}

// ---------------- causal depthwise conv (k=4) + SiLU ----------------
__global__ __launch_bounds__(192)
void k_conv(const ushort_t* __restrict__ xbc, const float* __restrict__ conv_w,
            const float* __restrict__ conv_b, ushort_t* __restrict__ xh,
            float* __restrict__ bmat, float* __restrict__ c_last){
  const int c0 = (blockIdx.x * 192 + threadIdx.x) * 4;
  const int t0 = blockIdx.y * TCH;
  const int b  = blockIdx.z;
  const size_t rowbase = (size_t)b * 2048;

  float cw[4][4], cb[4];
  #pragma unroll
  for (int j = 0; j < 4; ++j){
    cb[j] = conv_b[c0 + j];
    #pragma unroll
    for (int k = 0; k < 4; ++k) cw[j][k] = conv_w[(c0 + j) * 4 + k];
  }
  float h[3][4];
  #pragma unroll
  for (int k = 0; k < 3; ++k){
    int tt = t0 - 3 + k;
    if (tt >= 0){
      short4v v = *(const short4v*)&xbc[(rowbase + tt) * 2304 + c0];
      #pragma unroll
      for (int j = 0; j < 4; ++j) h[k][j] = bf2f((ushort_t)v[j]);
    } else {
      #pragma unroll
      for (int j = 0; j < 4; ++j) h[k][j] = 0.f;
    }
  }
  for (int t = t0; t < t0 + TCH; ++t){
    short4v v = *(const short4v*)&xbc[(rowbase + t) * 2304 + c0];
    float outv[4];
    #pragma unroll
    for (int j = 0; j < 4; ++j){
      float x = bf2f((ushort_t)v[j]);
      float a = cb[j] + h[0][j] * cw[j][0] + h[1][j] * cw[j][1] + h[2][j] * cw[j][2] + x * cw[j][3];
      outv[j] = a / (1.f + __expf(-a));
      h[0][j] = h[1][j]; h[1][j] = h[2][j]; h[2][j] = x;
    }
    if (c0 < 2048){
      ushort4v o;
      #pragma unroll
      for (int j = 0; j < 4; ++j) o[j] = f2bf(outv[j]);
      *(ushort4v*)&xh[(rowbase + t) * 2048 + c0] = o;
    } else if (c0 < 2176){
      f32x4 o;
      #pragma unroll
      for (int j = 0; j < 4; ++j) o[j] = outv[j];
      *(f32x4*)&bmat[(rowbase + t) * 128 + (c0 - 2048)] = o;
    } else if (t == 2047){
      f32x4 o;
      #pragma unroll
      for (int j = 0; j < 4; ++j) o[j] = outv[j];
      *(f32x4*)&c_last[b * 128 + (c0 - 2176)] = o;
    }
  }
}

// ---------------- g[b,t] = B_t . C_last ----------------
__global__ void k_gdot(const float* __restrict__ bmat, const float* __restrict__ c_last,
                       float* __restrict__ g){
  int r = threadIdx.x >> 5, n = threadIdx.x & 31;
  int row = blockIdx.x * 8 + r;
  int b = row >> 11;
  const float* bp = bmat + (size_t)row * 128;
  const float* cp = c_last + b * 128;
  float acc = 0.f;
  #pragma unroll
  for (int j = 0; j < 4; ++j) acc += bp[n + 32 * j] * cp[n + 32 * j];
  for (int s = 16; s; s >>= 1) acc += __shfl_down(acc, s, 32);
  if (n == 0) g[row] = acc;
}

// ---------------- per-(b,h) suffix scan -> coeff ----------------
__global__ void k_coeff(const float* __restrict__ dt_raw, const float* __restrict__ dt_bias,
                        const float* __restrict__ A_log, const float* __restrict__ g,
                        float* __restrict__ coeffw){
  __shared__ float csum[256];
  int bh = blockIdx.x;
  int b = bh >> 5, h = bh & 31;
  float Ah = -__expf(A_log[h]);
  float bias = dt_bias[h];
  int tid = threadIdx.x;
  size_t base = (size_t)b * 2048;
  float d[8], dts[8];
  #pragma unroll
  for (int j = 0; j < 8; ++j){
    int t = tid * 8 + j;
    float x = dt_raw[(base + t) * 32 + h] + bias;
    float sp = (x > 20.f) ? x : log1pf(__expf(x));
    dts[j] = sp;
    d[j] = sp * Ah;
  }
  float cs = 0.f;
  #pragma unroll
  for (int j = 0; j < 8; ++j) cs += d[j];
  csum[tid] = cs;
  __syncthreads();
  float suf = 0.f;
  for (int j = tid + 1; j < 256; ++j) suf += csum[j];
  float S = suf, outv[8];
  for (int j = 7; j >= 0; --j){ outv[j] = S; S += d[j]; }
  #pragma unroll
  for (int j = 0; j < 8; ++j){
    int t = tid * 8 + j;
    coeffw[(size_t)bh * 2048 + t] = __expf(outv[j]) * dts[j] * g[base + t];
  }
}

// ---------------- y_last partials: coalesced over channels ----------------
// block (b, ch): rows t in [ch*32, ch*32+32), thread owns 8 contiguous channels
__global__ __launch_bounds__(256)
void k_ysum2(const float* __restrict__ coeffw, const ushort_t* __restrict__ xh,
             float* __restrict__ ypart2){
  int b = blockIdx.x, ch = blockIdx.y;
  int tid = threadIdx.x;
  int c0 = tid * 8;
  int h = tid >> 3;
  const float* cw = coeffw + ((size_t)(b * 32 + h)) * 2048 + ch * 32;
  const ushort_t* xp = xh + ((size_t)b * 2048 + ch * 32) * 2048 + c0;
  float acc[8] = {0.f, 0.f, 0.f, 0.f, 0.f, 0.f, 0.f, 0.f};
  #pragma unroll 4
  for (int t = 0; t < 32; ++t){
    float cf = cw[t];
    short8 v = *(const short8*)&xp[(size_t)t * 2048];
    #pragma unroll
    for (int j = 0; j < 8; ++j) acc[j] += cf * bf2f((ushort_t)v[j]);
  }
  float* op = ypart2 + (((size_t)b * 64 + ch) * 2048) + c0;
  f32x4 o0, o1;
  #pragma unroll
  for (int j = 0; j < 4; ++j){ o0[j] = acc[j]; o1[j] = acc[4 + j]; }
  *(f32x4*)op = o0;
  *(f32x4*)(op + 4) = o1;
}
__global__ void k_ysum_r2(const float* __restrict__ ypart2, const ushort_t* __restrict__ xh,
                          const float* __restrict__ Dp, float* __restrict__ yfin){
  int i = blockIdx.x * 256 + threadIdx.x;      // 16384
  int b = i >> 11, c = i & 2047;
  float v = 0.f;
  #pragma unroll 8
  for (int ch = 0; ch < 64; ++ch)
    v += ypart2[(((size_t)b * 64 + ch) << 11) + c];
  v += Dp[c >> 6] * bf2f(xh[((size_t)b * 2048 + 2047) * 2048 + c]);
  yfin[i] = v;
}

// ---------------- z_last: wave per column ----------------
__global__ __launch_bounds__(64)
void k_zlast(const ushort_t* __restrict__ u16, const float* __restrict__ wzT,
             float* __restrict__ z_last){
  int col = blockIdx.x;
  int l = threadIdx.x;
  float acc[8] = {0.f, 0.f, 0.f, 0.f, 0.f, 0.f, 0.f, 0.f};
  const float* wp = wzT + (size_t)col * 1024;
  #pragma unroll 4
  for (int i = 0; i < 16; ++i){
    int k = i * 64 + l;
    float w = wp[k];
    #pragma unroll
    for (int b = 0; b < 8; ++b)
      acc[b] += bf2f(u16[((size_t)b * 2048 + 2047) * 1024 + k]) * w;
  }
  #pragma unroll
  for (int b = 0; b < 8; ++b){
    float v = acc[b];
    for (int s = 32; s; s >>= 1) v += __shfl_down(v, s, 64);
    if (l == 0) z_last[b * 2048 + col] = v;
  }
}

// ---------------- gated RMSNorm ----------------
__global__ void k_norm(const float* __restrict__ yfin, const float* __restrict__ z_last,
                       const float* __restrict__ norm_w, float* __restrict__ yn){
  __shared__ float red[256];
  int b = blockIdx.x, tid = threadIdx.x;
  float vals[8], ss = 0.f;
  #pragma unroll
  for (int j = 0; j < 8; ++j){
    int c = tid + 256 * j;
    float z = z_last[b * 2048 + c];
    float yg = yfin[b * 2048 + c] * (z / (1.f + __expf(-z)));
    vals[j] = yg; ss += yg * yg;
  }
  red[tid] = ss; __syncthreads();
  for (int s = 128; s; s >>= 1){
    if (tid < s) red[tid] += red[tid + s];
    __syncthreads();
  }
  float scale = rsqrtf(red[0] / 2048.f + EPSV);
  #pragma unroll
  for (int j = 0; j < 8; ++j){
    int c = tid + 256 * j;
    yn[b * 2048 + c] = vals[j] * scale * norm_w[c];
  }
}

// ---------------- out projection: wave per column ----------------
__global__ __launch_bounds__(64)
void k_outproj(const float* __restrict__ yn, const float* __restrict__ wot,
               float* __restrict__ o){
  int col = blockIdx.x;
  int l = threadIdx.x;
  float acc[8] = {0.f, 0.f, 0.f, 0.f, 0.f, 0.f, 0.f, 0.f};
  const float* wp = wot + (size_t)col * 2048;
  #pragma unroll 4
  for (int i = 0; i < 32; ++i){
    int k = i * 64 + l;
    float w = wp[k];
    #pragma unroll
    for (int b = 0; b < 8; ++b)
      acc[b] += yn[b * 2048 + k] * w;
  }
  #pragma unroll
  for (int b = 0; b < 8; ++b){
    float v = acc[b];
    for (int s = 32; s; s >>= 1) v += __shfl_down(v, s, 64);
    if (l == 0) o[b * 1024 + col] = v;
  }
}

// ---------------- head: wave per output column ----------------
__global__ __launch_bounds__(64)
void k_head(const float* __restrict__ o, const float* __restrict__ wht,
            const float* __restrict__ b_head, float* __restrict__ out){
  int j = blockIdx.x;
  int l = threadIdx.x;
  float acc[8] = {0.f, 0.f, 0.f, 0.f, 0.f, 0.f, 0.f, 0.f};
  const float* wp = wht + (size_t)j * 1024;
  #pragma unroll 4
  for (int i = 0; i < 16; ++i){
    int k = i * 64 + l;
    float w = wp[k];
    #pragma unroll
    for (int b = 0; b < 8; ++b)
      acc[b] += o[b * 1024 + k] * w;
  }
  #pragma unroll
  for (int b = 0; b < 8; ++b){
    float v = acc[b];
    for (int s = 32; s; s >>= 1) v += __shfl_down(v, s, 64);
    if (l == 0) out[b * 64 + j] = v + b_head[j];
  }
}

extern "C" void kernel_launch(void* const* d_in, const int* in_sizes, int n_in,
                              void* d_out, int out_size, void* d_ws, size_t ws_size,
                              hipStream_t stream){
  (void)in_sizes; (void)n_in; (void)out_size; (void)ws_size;
  const float* x       = (const float*)d_in[0];
  const float* w_proj  = (const float*)d_in[1];
  const float* b_proj  = (const float*)d_in[2];
  const float* w_in    = (const float*)d_in[3];
  const float* conv_w  = (const float*)d_in[4];
  const float* conv_b  = (const float*)d_in[5];
  const float* A_log   = (const float*)d_in[6];
  const float* dt_bias = (const float*)d_in[7];
  const float* Dp      = (const float*)d_in[8];
  const float* norm_w  = (const float*)d_in[9];
  const float* w_out   = (const float*)d_in[10];
  const float* w_head  = (const float*)d_in[11];
  const float* b_head  = (const float*)d_in[12];
  float* out = (float*)d_out;

  char* ws = (char*)d_ws;
  size_t off = 0;
  auto alloc = [&](size_t bytes)->char*{
    char* p = ws + off; off += (bytes + 255) & ~(size_t)255; return p;
  };
  ushort_t* xb    = (ushort_t*)alloc((size_t)M_ROWS * 64 * 2);
  ushort_t* w1t   = (ushort_t*)alloc((size_t)1024 * 64 * 2);
  ushort_t* w2t   = (ushort_t*)alloc((size_t)2304 * 1024 * 2);
  ushort_t* wdt   = (ushort_t*)alloc((size_t)32 * 2048 * 2);
  float*    wzT   = (float*)alloc((size_t)2048 * 1024 * 4);
  float*    wot   = (float*)alloc((size_t)1024 * 2048 * 4);
  float*    wht   = (float*)alloc((size_t)64 * 1024 * 4);
  ushort_t* u16   = (ushort_t*)alloc((size_t)M_ROWS * 1024 * 2);
  ushort_t* xbc   = (ushort_t*)alloc((size_t)M_ROWS * 2304 * 2);
  float*    dtr   = (float*)alloc((size_t)M_ROWS * 32 * 4);
  ushort_t* xh    = (ushort_t*)alloc((size_t)M_ROWS * 2048 * 2);
  float*    bmat  = (float*)alloc((size_t)M_ROWS * 128 * 4);
  float*    clast = (float*)alloc((size_t)8 * 128 * 4);
  float*    g     = (float*)alloc((size_t)M_ROWS * 4);
  float*    cfw   = (float*)alloc((size_t)256 * 2048 * 4);
  float*    ypart = (float*)alloc((size_t)8 * 64 * 2048 * 4);
  float*    yfin  = (float*)alloc((size_t)8 * 2048 * 4);
  float*    zl    = (float*)alloc((size_t)8 * 2048 * 4);
  float*    yn    = (float*)alloc((size_t)8 * 2048 * 4);
  float*    ov    = (float*)alloc((size_t)8 * 1024 * 4);

  k_cvt_bf16<<<(M_ROWS * 64 + 255) / 256, 256, 0, stream>>>(x, xb, M_ROWS * 64);
  k_w1t<<<(65536 + 255) / 256, 256, 0, stream>>>(w_proj, w1t);
  dim3 gw2(36, 16);
  k_w2t<<<gw2, 256, 0, stream>>>(w_in, w2t);
  k_wdt<<<(32768 + 255) / 256, 256, 0, stream>>>(w_in, wdt);
  dim3 gtz(32, 16);
  k_transf32<<<gtz, 256, 0, stream>>>(w_in, wzT, 1024, 4384, 0);
  dim3 gto(16, 32);
  k_transf32<<<gto, 256, 0, stream>>>(w_out, wot, 2048, 1024, 0);
  dim3 gth(1, 16);
  k_transf32<<<gth, 256, 0, stream>>>(w_head, wht, 1024, 64, 0);

  k_gemm_bf16<<<(1024 / 128) * (M_ROWS / 128), 256, 0, stream>>>(xb, w1t, b_proj, u16, 64, 1024, 1024 / 128);

  k_gemm256<<<(M_ROWS / 256) * (2304 / 256), 512, 0, stream>>>(u16, w2t, xbc, 2304, 2304 / 256);

  k_dtg<<<M_ROWS / 128, 256, 0, stream>>>(u16, wdt, dtr);

  dim3 gc(3, L_SEQ / TCH, BATCH);
  k_conv<<<gc, 192, 0, stream>>>(xbc, conv_w, conv_b, xh, bmat, clast);

  k_gdot<<<M_ROWS / 8, 256, 0, stream>>>(bmat, clast, g);
  k_coeff<<<256, 256, 0, stream>>>(dtr, dt_bias, A_log, g, cfw);

  dim3 gy(8, 64);
  k_ysum2<<<gy, 256, 0, stream>>>(cfw, xh, ypart);
  k_ysum_r2<<<M_ROWS / 256, 256, 0, stream>>>(ypart, xh, Dp, yfin);

  k_zlast<<<2048, 64, 0, stream>>>(u16, wzT, zl);
  k_norm<<<8, 256, 0, stream>>>(yfin, zl, norm_w, yn);
  k_outproj<<<1024, 64, 0, stream>>>(yn, wot, ov);
  k_head<<<64, 64, 0, stream>>>(ov, wht, b_head, out);
}

// Round 6
// 228.193 us; speedup vs baseline: 3.3244x; 1.1741x over previous
//
#include <hip/hip_runtime.h>
#include <hip/hip_bf16.h>
#include <stdint.h>

typedef unsigned short ushort_t;
typedef __attribute__((ext_vector_type(8))) short short8;
typedef __attribute__((ext_vector_type(4))) short short4v;
typedef __attribute__((ext_vector_type(4))) unsigned short ushort4v;
typedef __attribute__((ext_vector_type(4))) float f32x4;

#define L_SEQ   2048
#define BATCH   8
#define M_ROWS  16384          // BATCH*L_SEQ
#define EPSV    1e-5f

__device__ __forceinline__ float bf2f(ushort_t u){
  union { uint32_t i; float f; } v; v.i = ((uint32_t)u) << 16; return v.f;
}
__device__ __forceinline__ ushort_t f2bf(float f){
  union { float f; uint32_t i; } v; v.f = f;
  uint32_t r = v.i + 0x7fffu + ((v.i >> 16) & 1u);
  return (ushort_t)(r >> 16);
}

// ---------------- fused prep: cvt + w1t + wdt + 4 transposes, section-dispatched ----------------
__global__ __launch_bounds__(256)
void k_prep(const float* __restrict__ x, const float* __restrict__ w_proj,
            const float* __restrict__ w_in, const float* __restrict__ w_out,
            const float* __restrict__ w_head,
            ushort_t* __restrict__ xb, ushort_t* __restrict__ w1t,
            ushort_t* __restrict__ w2t, ushort_t* __restrict__ wdt,
            float* __restrict__ wzT, float* __restrict__ wot, float* __restrict__ wht){
  __shared__ float tile[64][65];
  int bx = blockIdx.x, tid = threadIdx.x;
  if (bx < 4096){                          // x -> bf16
    int i = bx * 256 + tid;
    xb[i] = f2bf(x[i]);
    return;
  }
  bx -= 4096;
  if (bx < 256){                           // w1t[j*64+k] = w_proj[k*1024+j]
    int i = bx * 256 + tid; int k = i >> 10, j = i & 1023;
    w1t[j * 64 + k] = f2bf(w_proj[i]);
    return;
  }
  bx -= 256;
  if (bx < 128){                           // dt weights hi/lo split
    int i = bx * 256 + tid; int n = i >> 10, k = i & 1023;
    float w = w_in[(size_t)k * 4384 + 4352 + n];
    ushort_t hi = f2bf(w);
    wdt[n * 2048 + k] = hi;
    wdt[n * 2048 + 1024 + k] = f2bf(w - bf2f(hi));
    return;
  }
  bx -= 128;
  const float* src; float* dstf = nullptr; ushort_t* dstb = nullptr;
  int R, C, colOff, j0, k0;
  if (bx < 576){       src = w_in;   dstb = w2t; R = 1024; C = 4384; colOff = 2048; j0 = (bx % 36) * 64; k0 = (bx / 36) * 64; }
  else if ((bx -= 576) < 512){ src = w_in;  dstf = wzT; R = 1024; C = 4384; colOff = 0; j0 = (bx % 32) * 64; k0 = (bx / 32) * 64; }
  else if ((bx -= 512) < 512){ src = w_out; dstf = wot; R = 2048; C = 1024; colOff = 0; j0 = (bx % 16) * 64; k0 = (bx / 16) * 64; }
  else { bx -= 512;    src = w_head; dstf = wht; R = 1024; C = 64;   colOff = 0; j0 = 0;             k0 = bx * 64; }
  int tx = tid & 63, ty = tid >> 6;
  #pragma unroll
  for (int i = 0; i < 16; ++i){
    int kk = ty * 16 + i;
    tile[kk][tx] = src[(size_t)(k0 + kk) * C + colOff + j0 + tx];
  }
  __syncthreads();
  #pragma unroll
  for (int i = 0; i < 16; ++i){
    int jj = ty * 16 + i;
    if (dstb) dstb[(size_t)(j0 + jj) * R + k0 + tx] = f2bf(tile[tx][jj]);
    else      dstf[(size_t)(j0 + jj) * R + k0 + tx] = tile[tx][jj];
  }
}

// ---------------- async global->LDS ----------------
__device__ __forceinline__ void gload16(const void* g, void* l){
  __builtin_amdgcn_global_load_lds((const __attribute__((address_space(1))) void*)g,
                                   (__attribute__((address_space(3))) void*)l, 16, 0, 0);
}

// ---------------- phase fences ----------------
__device__ __forceinline__ void phase_enter(){
  __builtin_amdgcn_sched_barrier(0);
  asm volatile("" ::: "memory");
  __builtin_amdgcn_s_barrier();
  asm volatile("" ::: "memory");
  __builtin_amdgcn_sched_barrier(0);
  __builtin_amdgcn_s_setprio(1);
}
__device__ __forceinline__ void phase_exit(){
  __builtin_amdgcn_s_setprio(0);
  __builtin_amdgcn_sched_barrier(0);
  asm volatile("" ::: "memory");
  __builtin_amdgcn_s_barrier();
  asm volatile("" ::: "memory");
  __builtin_amdgcn_sched_barrier(0);
}
__device__ __forceinline__ void phase_exit_vm(){
  __builtin_amdgcn_s_setprio(0);
  __builtin_amdgcn_sched_barrier(0);
  asm volatile("s_waitcnt vmcnt(4)" ::: "memory");
  __builtin_amdgcn_s_barrier();
  asm volatile("" ::: "memory");
  __builtin_amdgcn_sched_barrier(0);
}

// ---------------- 256x256 8-phase bf16 GEMM (K=1024, R4 schedule): C = A * Bt^T ----------------
__global__ __launch_bounds__(512, 1)
void k_gemm256(const ushort_t* __restrict__ A, const ushort_t* __restrict__ Bt,
               ushort_t* __restrict__ C, int N, int nbx){
  __shared__ ushort_t lds[65536];
  const int tid = threadIdx.x;
  const int lane = tid & 63;
  const int wave = tid >> 6;
  const int wr = wave >> 2, wc = wave & 3;
  const int l15 = lane & 15, l4 = lane >> 4;

  const int nwg = gridDim.x, cpx = nwg >> 3;
  const int swz = ((int)blockIdx.x & 7) * cpx + ((int)blockIdx.x >> 3);
  const int m0 = (swz / nbx) * 256, n0 = (swz % nbx) * 256;

  const int stage_eg = ((tid & 7) * 8) ^ (((tid >> 3) & 7) << 3);
  const int e0 = (l4 * 8) ^ ((l15 & 7) << 3);
  const int e1 = (32 + l4 * 8) ^ ((l15 & 7) << 3);
  const int aoff_base = wr * 8192 + l15 * 64;
  const int boff_base = 16384 + (wc >> 1) * 8192 + ((wc & 1) * 64 + l15) * 64;

  auto stage = [&](int t, int isB, int h, int dbuf){
    if (t < 16){
      const ushort_t* src = isB ? Bt : A;
      const int row0 = (isB ? n0 : m0) + h * 128 + (tid >> 3);
      const int dst = dbuf * 32768 + isB * 16384 + h * 8192 + tid * 8;
      gload16(src + (size_t)row0 * 1024 + t * 64 + stage_eg, &lds[dst]);
      gload16(src + (size_t)(row0 + 64) * 1024 + t * 64 + stage_eg, &lds[dst + 4096]);
    }
  };

  f32x4 acc[8][4];
  #pragma unroll
  for (int m = 0; m < 8; ++m)
    #pragma unroll
    for (int n = 0; n < 4; ++n)
      #pragma unroll
      for (int r = 0; r < 4; ++r) acc[m][n][r] = 0.f;

  stage(0, 1, 0, 0); stage(0, 1, 1, 0);
  stage(0, 0, 0, 0); stage(0, 0, 1, 0);
  stage(1, 1, 0, 1); stage(1, 1, 1, 1);
  asm volatile("s_waitcnt vmcnt(4)" ::: "memory");
  __builtin_amdgcn_s_barrier();
  asm volatile("" ::: "memory");

  short8 aF[4][2], bK[2][2], bF[2][2];

  for (int i = 0; i < 8; ++i){
    #pragma unroll
    for (int hh = 0; hh < 2; ++hh){
      const int bufo = hh * 32768;
      const int tA_ = (hh == 0) ? 2 * i + 1 : 2 * i + 2;
      const int dbA = (hh == 0) ? 1 : 0;
      const int tB_ = (hh == 0) ? 2 * i + 2 : 2 * i + 3;
      const int dbB = (hh == 0) ? 0 : 1;
      const int ao = bufo + aoff_base;
      const int bo = bufo + boff_base;
      // ---- ph1: read A m0-3 + B n0-1 ; stage A0 ----
      #pragma unroll
      for (int m = 0; m < 4; ++m){
        aF[m][0] = *(const short8*)&lds[ao + m * 1024 + e0];
        aF[m][1] = *(const short8*)&lds[ao + m * 1024 + e1];
      }
      #pragma unroll
      for (int n = 0; n < 2; ++n){
        bK[n][0] = *(const short8*)&lds[bo + n * 1024 + e0];
        bK[n][1] = *(const short8*)&lds[bo + n * 1024 + e1];
      }
      stage(tA_, 0, 0, dbA);
      phase_enter();
      #pragma unroll
      for (int m = 0; m < 4; ++m)
        #pragma unroll
        for (int n = 0; n < 2; ++n){
          acc[m][n] = __builtin_amdgcn_mfma_f32_16x16x32_bf16(aF[m][0], bK[n][0], acc[m][n], 0, 0, 0);
          acc[m][n] = __builtin_amdgcn_mfma_f32_16x16x32_bf16(aF[m][1], bK[n][1], acc[m][n], 0, 0, 0);
        }
      phase_exit();
      // ---- ph2: read B n2-3 ; stage A1 ----
      #pragma unroll
      for (int n = 0; n < 2; ++n){
        bF[n][0] = *(const short8*)&lds[bo + (n + 2) * 1024 + e0];
        bF[n][1] = *(const short8*)&lds[bo + (n + 2) * 1024 + e1];
      }
      stage(tA_, 0, 1, dbA);
      phase_enter();
      #pragma unroll
      for (int m = 0; m < 4; ++m)
        #pragma unroll
        for (int n = 0; n < 2; ++n){
          acc[m][n + 2] = __builtin_amdgcn_mfma_f32_16x16x32_bf16(aF[m][0], bF[n][0], acc[m][n + 2], 0, 0, 0);
          acc[m][n + 2] = __builtin_amdgcn_mfma_f32_16x16x32_bf16(aF[m][1], bF[n][1], acc[m][n + 2], 0, 0, 0);
        }
      phase_exit();
      // ---- ph3: read A m4-7 ; stage B0 ----
      #pragma unroll
      for (int m = 0; m < 4; ++m){
        aF[m][0] = *(const short8*)&lds[ao + (m + 4) * 1024 + e0];
        aF[m][1] = *(const short8*)&lds[ao + (m + 4) * 1024 + e1];
      }
      stage(tB_, 1, 0, dbB);
      phase_enter();
      #pragma unroll
      for (int m = 0; m < 4; ++m)
        #pragma unroll
        for (int n = 0; n < 2; ++n){
          acc[m + 4][n + 2] = __builtin_amdgcn_mfma_f32_16x16x32_bf16(aF[m][0], bF[n][0], acc[m + 4][n + 2], 0, 0, 0);
          acc[m + 4][n + 2] = __builtin_amdgcn_mfma_f32_16x16x32_bf16(aF[m][1], bF[n][1], acc[m + 4][n + 2], 0, 0, 0);
        }
      phase_exit();
      // ---- ph4: no reads ; stage B1 ; counted vm wait ----
      stage(tB_, 1, 1, dbB);
      phase_enter();
      #pragma unroll
      for (int m = 0; m < 4; ++m)
        #pragma unroll
        for (int n = 0; n < 2; ++n){
          acc[m + 4][n] = __builtin_amdgcn_mfma_f32_16x16x32_bf16(aF[m][0], bK[n][0], acc[m + 4][n], 0, 0, 0);
          acc[m + 4][n] = __builtin_amdgcn_mfma_f32_16x16x32_bf16(aF[m][1], bK[n][1], acc[m + 4][n], 0, 0, 0);
        }
      phase_exit_vm();
    }
  }

  #pragma unroll
  for (int m = 0; m < 8; ++m){
    const int row = m0 + wr * 128 + m * 16 + l4 * 4;
    #pragma unroll
    for (int n = 0; n < 4; ++n){
      const int col = n0 + wc * 64 + n * 16 + l15;
      #pragma unroll
      for (int r = 0; r < 4; ++r)
        C[(size_t)(row + r) * N + col] = f2bf(acc[m][n][r]);
    }
  }
}

// ---------------- 128^2 bf16 MFMA GEMM (GEMM1) ----------------
__global__ __launch_bounds__(256)
void k_gemm_bf16(const ushort_t* __restrict__ A, const ushort_t* __restrict__ Bt,
                 const float* __restrict__ bias, ushort_t* __restrict__ C,
                 int K, int N, int nbx){
  __shared__ ushort_t tA[128 * 32];
  __shared__ ushort_t tB[128 * 32];
  const int nwg = gridDim.x;
  const int cpx = nwg >> 3;
  const int bid = blockIdx.x;
  const int swz = (bid & 7) * cpx + (bid >> 3);
  const int m0 = (swz / nbx) * 128, n0 = (swz % nbx) * 128;

  const int tid  = threadIdx.x;
  const int wave = tid >> 6, lane = tid & 63;
  const int wr = wave >> 1, wc = wave & 1;
  const int l15 = lane & 15, l4 = lane >> 4;
  const int srow  = lane >> 2;
  const int skoff = (lane & 3) * 8;

  f32x4 acc[4][4];
  #pragma unroll
  for (int m = 0; m < 4; ++m)
    #pragma unroll
    for (int n = 0; n < 4; ++n)
      #pragma unroll
      for (int r = 0; r < 4; ++r) acc[m][n][r] = 0.f;

  for (int k0 = 0; k0 < K; k0 += 32){
    #pragma unroll
    for (int r = 0; r < 2; ++r){
      int chunk = r * 4 + wave;
      int rr = chunk * 16 + srow;
      gload16(A  + (size_t)(m0 + rr) * K + k0 + skoff, &tA[chunk * 512]);
      gload16(Bt + (size_t)(n0 + rr) * K + k0 + skoff, &tB[chunk * 512]);
    }
    __syncthreads();
    short8 af[4], bfv[4];
    #pragma unroll
    for (int m = 0; m < 4; ++m)
      af[m] = *(const short8*)&tA[(wr * 64 + m * 16 + l15) * 32 + l4 * 8];
    #pragma unroll
    for (int n = 0; n < 4; ++n)
      bfv[n] = *(const short8*)&tB[(wc * 64 + n * 16 + l15) * 32 + l4 * 8];
    #pragma unroll
    for (int m = 0; m < 4; ++m)
      #pragma unroll
      for (int n = 0; n < 4; ++n)
        acc[m][n] = __builtin_amdgcn_mfma_f32_16x16x32_bf16(af[m], bfv[n], acc[m][n], 0, 0, 0);
    __syncthreads();
  }
  #pragma unroll
  for (int n = 0; n < 4; ++n){
    int col = n0 + wc * 64 + n * 16 + l15;
    float bv = bias ? bias[col] : 0.f;
    #pragma unroll
    for (int m = 0; m < 4; ++m){
      int rowb = m0 + wr * 64 + m * 16 + l4 * 4;
      #pragma unroll
      for (int r = 0; r < 4; ++r)
        C[(size_t)(rowb + r) * N + col] = f2bf(acc[m][n][r] + bv);
    }
  }
}

// ---------------- dt GEMM (fp32 out, single A pass, dual-B accumulate) ----------------
__global__ __launch_bounds__(256)
void k_dtg(const ushort_t* __restrict__ A, const ushort_t* __restrict__ Bt,
           float* __restrict__ dtr){
  __shared__ ushort_t tA[128 * 32];
  __shared__ ushort_t tBh[32 * 32];
  __shared__ ushort_t tBl[32 * 32];
  const int tid  = threadIdx.x;
  const int wave = tid >> 6, lane = tid & 63;
  const int l15 = lane & 15, l4 = lane >> 4;
  const int srow  = lane >> 2;
  const int skoff = (lane & 3) * 8;
  const int m0 = blockIdx.x * 128;

  f32x4 acc[2][2];
  #pragma unroll
  for (int m = 0; m < 2; ++m)
    #pragma unroll
    for (int n = 0; n < 2; ++n)
      #pragma unroll
      for (int r = 0; r < 4; ++r) acc[m][n][r] = 0.f;

  for (int k0 = 0; k0 < 1024; k0 += 32){
    #pragma unroll
    for (int r = 0; r < 2; ++r){
      int chunk = r * 4 + wave;
      int rr = chunk * 16 + srow;
      gload16(A + (size_t)(m0 + rr) * 1024 + k0 + skoff, &tA[chunk * 512]);
    }
    if (wave < 2){
      int rr = wave * 16 + srow;
      gload16(Bt + (size_t)rr * 2048 + k0 + skoff, &tBh[wave * 512]);
    } else if (wave < 4){
      int rr = (wave - 2) * 16 + srow;
      gload16(Bt + (size_t)rr * 2048 + 1024 + k0 + skoff, &tBl[(wave - 2) * 512]);
    }
    __syncthreads();
    short8 af[2], bh[2], bl[2];
    #pragma unroll
    for (int m = 0; m < 2; ++m)
      af[m] = *(const short8*)&tA[(wave * 32 + m * 16 + l15) * 32 + l4 * 8];
    #pragma unroll
    for (int n = 0; n < 2; ++n){
      bh[n] = *(const short8*)&tBh[(n * 16 + l15) * 32 + l4 * 8];
      bl[n] = *(const short8*)&tBl[(n * 16 + l15) * 32 + l4 * 8];
    }
    #pragma unroll
    for (int m = 0; m < 2; ++m)
      #pragma unroll
      for (int n = 0; n < 2; ++n){
        acc[m][n] = __builtin_amdgcn_mfma_f32_16x16x32_bf16(af[m], bh[n], acc[m][n], 0, 0, 0);
        acc[m][n] = __builtin_amdgcn_mfma_f32_16x16x32_bf16(af[m], bl[n], acc[m][n], 0, 0, 0);
      }
    __syncthreads();
  }
  #pragma unroll
  for (int n = 0; n < 2; ++n){
    int col = n * 16 + l15;
    #pragma unroll
    for (int m = 0; m < 2; ++m){
      int rowb = m0 + wave * 32 + m * 16 + l4 * 4;
      #pragma unroll
      for (int r = 0; r < 4; ++r)
        dtr[(size_t)(rowb + r) * 32 + col] = acc[m][n][r];
    }
  }
}

// ---------------- conv+SiLU for B/C channels only (256 of 2304) ----------------
__global__ __launch_bounds__(256)
void k_convbc(const ushort_t* __restrict__ xbc, const float* __restrict__ conv_w,
              const float* __restrict__ conv_b, float* __restrict__ bmat,
              float* __restrict__ c_last){
  const int c0 = 2048 + (threadIdx.x & 63) * 4;
  const int tl = threadIdx.x >> 6;
  const int t0 = blockIdx.x * 64 + tl * 16;
  const int b  = blockIdx.y;
  const size_t rowbase = (size_t)b * 2048;

  float cw[4][4], cb[4];
  #pragma unroll
  for (int j = 0; j < 4; ++j){
    cb[j] = conv_b[c0 + j];
    f32x4 w4 = *(const f32x4*)&conv_w[(c0 + j) * 4];
    #pragma unroll
    for (int k = 0; k < 4; ++k) cw[j][k] = w4[k];
  }
  float h[3][4];
  #pragma unroll
  for (int k = 0; k < 3; ++k){
    int tt = t0 - 3 + k;
    if (tt >= 0){
      short4v v = *(const short4v*)&xbc[(rowbase + tt) * 2304 + c0];
      #pragma unroll
      for (int j = 0; j < 4; ++j) h[k][j] = bf2f((ushort_t)v[j]);
    } else {
      #pragma unroll
      for (int j = 0; j < 4; ++j) h[k][j] = 0.f;
    }
  }
  for (int t = t0; t < t0 + 16; ++t){
    short4v v = *(const short4v*)&xbc[(rowbase + t) * 2304 + c0];
    float outv[4];
    #pragma unroll
    for (int j = 0; j < 4; ++j){
      float x = bf2f((ushort_t)v[j]);
      float a = cb[j] + h[0][j] * cw[j][0] + h[1][j] * cw[j][1] + h[2][j] * cw[j][2] + x * cw[j][3];
      outv[j] = a / (1.f + __expf(-a));
      h[0][j] = h[1][j]; h[1][j] = h[2][j]; h[2][j] = x;
    }
    if (c0 < 2176){
      f32x4 o;
      #pragma unroll
      for (int j = 0; j < 4; ++j) o[j] = outv[j];
      *(f32x4*)&bmat[(rowbase + t) * 128 + (c0 - 2048)] = o;
    } else if (t == 2047){
      f32x4 o;
      #pragma unroll
      for (int j = 0; j < 4; ++j) o[j] = outv[j];
      *(f32x4*)&c_last[b * 128 + (c0 - 2176)] = o;
    }
  }
}

// ---------------- g[b,t] = B_t . C_last ----------------
__global__ void k_gdot(const float* __restrict__ bmat, const float* __restrict__ c_last,
                       float* __restrict__ g){
  int r = threadIdx.x >> 5, n = threadIdx.x & 31;
  int row = blockIdx.x * 8 + r;
  int b = row >> 11;
  const float* bp = bmat + (size_t)row * 128;
  const float* cp = c_last + b * 128;
  float acc = 0.f;
  #pragma unroll
  for (int j = 0; j < 4; ++j) acc += bp[n + 32 * j] * cp[n + 32 * j];
  for (int s = 16; s; s >>= 1) acc += __shfl_down(acc, s, 32);
  if (n == 0) g[row] = acc;
}

// ---------------- per-(b,h) suffix scan -> coeff ----------------
__global__ void k_coeff(const float* __restrict__ dt_raw, const float* __restrict__ dt_bias,
                        const float* __restrict__ A_log, const float* __restrict__ g,
                        float* __restrict__ coeffw){
  __shared__ float csum[256];
  int bh = blockIdx.x;
  int b = bh >> 5, h = bh & 31;
  float Ah = -__expf(A_log[h]);
  float bias = dt_bias[h];
  int tid = threadIdx.x;
  size_t base = (size_t)b * 2048;
  float d[8], dts[8];
  #pragma unroll
  for (int j = 0; j < 8; ++j){
    int t = tid * 8 + j;
    float x = dt_raw[(base + t) * 32 + h] + bias;
    float sp = (x > 20.f) ? x : log1pf(__expf(x));
    dts[j] = sp;
    d[j] = sp * Ah;
  }
  float cs = 0.f;
  #pragma unroll
  for (int j = 0; j < 8; ++j) cs += d[j];
  csum[tid] = cs;
  __syncthreads();
  float suf = 0.f;
  for (int j = tid + 1; j < 256; ++j) suf += csum[j];
  float S = suf, outv[8];
  for (int j = 7; j >= 0; --j){ outv[j] = S; S += d[j]; }
  #pragma unroll
  for (int j = 0; j < 8; ++j){
    int t = tid * 8 + j;
    coeffw[(size_t)bh * 2048 + t] = __expf(outv[j]) * dts[j] * g[base + t];
  }
}

// ---------------- fused conv(x-part)+SiLU+weighted time-sum ----------------
// block (b, ch): t in [ch*32, ch*32+32); thread owns 8 contiguous channels of 2048
__global__ __launch_bounds__(256)
void k_ysum2f(const float* __restrict__ coeffw, const ushort_t* __restrict__ xbc,
              const float* __restrict__ conv_w, const float* __restrict__ conv_b,
              float* __restrict__ ypart2, ushort_t* __restrict__ xhlast){
  int b = blockIdx.x, ch = blockIdx.y;
  int tid = threadIdx.x;
  int c0 = tid * 8;
  int h = tid >> 3;
  int t0 = ch * 32;
  const float* cwt = coeffw + ((size_t)(b * 32 + h)) * 2048 + t0;
  const size_t rowbase = (size_t)b * 2048;

  float wv[8][4], cb[8];
  #pragma unroll
  for (int j = 0; j < 8; ++j){
    f32x4 w4 = *(const f32x4*)&conv_w[(c0 + j) * 4];
    #pragma unroll
    for (int k = 0; k < 4; ++k) wv[j][k] = w4[k];
    cb[j] = conv_b[c0 + j];
  }
  float h0[8], h1[8], h2[8];
  {
    float* hs[3] = {h0, h1, h2};
    #pragma unroll
    for (int k = 0; k < 3; ++k){
      int tt = t0 - 3 + k;
      if (tt >= 0){
        short8 v = *(const short8*)&xbc[(rowbase + tt) * 2304 + c0];
        #pragma unroll
        for (int j = 0; j < 8; ++j) hs[k][j] = bf2f((ushort_t)v[j]);
      } else {
        #pragma unroll
        for (int j = 0; j < 8; ++j) hs[k][j] = 0.f;
      }
    }
  }
  float acc[8] = {0.f, 0.f, 0.f, 0.f, 0.f, 0.f, 0.f, 0.f};
  float sil[8];
  for (int t = 0; t < 32; ++t){
    short8 v = *(const short8*)&xbc[(rowbase + t0 + t) * 2304 + c0];
    float cf = cwt[t];
    #pragma unroll
    for (int j = 0; j < 8; ++j){
      float xv = bf2f((ushort_t)v[j]);
      float a = cb[j] + h0[j] * wv[j][0] + h1[j] * wv[j][1] + h2[j] * wv[j][2] + xv * wv[j][3];
      float s = a / (1.f + __expf(-a));
      sil[j] = s;
      acc[j] += cf * s;
      h0[j] = h1[j]; h1[j] = h2[j]; h2[j] = xv;
    }
  }
  float* op = ypart2 + (((size_t)b * 64 + ch) * 2048) + c0;
  f32x4 o0, o1;
  #pragma unroll
  for (int j = 0; j < 4; ++j){ o0[j] = acc[j]; o1[j] = acc[4 + j]; }
  *(f32x4*)op = o0;
  *(f32x4*)(op + 4) = o1;
  if (ch == 63){
    ushort4v s0, s1;
    #pragma unroll
    for (int j = 0; j < 4; ++j){ s0[j] = f2bf(sil[j]); s1[j] = f2bf(sil[4 + j]); }
    *(ushort4v*)&xhlast[b * 2048 + c0] = s0;
    *(ushort4v*)&xhlast[b * 2048 + c0 + 4] = s1;
  }
}

// ---------------- reduce ypart chunks + D-term ----------------
__global__ void k_ysum_r2(const float* __restrict__ ypart2, const ushort_t* __restrict__ xhlast,
                          const float* __restrict__ Dp, float* __restrict__ yfin){
  int i = blockIdx.x * 256 + threadIdx.x;      // 16384
  int b = i >> 11, c = i & 2047;
  float v = 0.f;
  #pragma unroll 8
  for (int ch = 0; ch < 64; ++ch)
    v += ypart2[(((size_t)b * 64 + ch) << 11) + c];
  v += Dp[c >> 6] * bf2f(xhlast[b * 2048 + c]);
  yfin[i] = v;
}

// ---------------- z_last: wave per column ----------------
__global__ __launch_bounds__(64)
void k_zlast(const ushort_t* __restrict__ u16, const float* __restrict__ wzT,
             float* __restrict__ z_last){
  int col = blockIdx.x;
  int l = threadIdx.x;
  float acc[8] = {0.f, 0.f, 0.f, 0.f, 0.f, 0.f, 0.f, 0.f};
  const float* wp = wzT + (size_t)col * 1024;
  #pragma unroll 4
  for (int i = 0; i < 16; ++i){
    int k = i * 64 + l;
    float w = wp[k];
    #pragma unroll
    for (int b = 0; b < 8; ++b)
      acc[b] += bf2f(u16[((size_t)b * 2048 + 2047) * 1024 + k]) * w;
  }
  #pragma unroll
  for (int b = 0; b < 8; ++b){
    float v = acc[b];
    for (int s = 32; s; s >>= 1) v += __shfl_down(v, s, 64);
    if (l == 0) z_last[b * 2048 + col] = v;
  }
}

// ---------------- gated RMSNorm ----------------
__global__ void k_norm(const float* __restrict__ yfin, const float* __restrict__ z_last,
                       const float* __restrict__ norm_w, float* __restrict__ yn){
  __shared__ float red[256];
  int b = blockIdx.x, tid = threadIdx.x;
  float vals[8], ss = 0.f;
  #pragma unroll
  for (int j = 0; j < 8; ++j){
    int c = tid + 256 * j;
    float z = z_last[b * 2048 + c];
    float yg = yfin[b * 2048 + c] * (z / (1.f + __expf(-z)));
    vals[j] = yg; ss += yg * yg;
  }
  red[tid] = ss; __syncthreads();
  for (int s = 128; s; s >>= 1){
    if (tid < s) red[tid] += red[tid + s];
    __syncthreads();
  }
  float scale = rsqrtf(red[0] / 2048.f + EPSV);
  #pragma unroll
  for (int j = 0; j < 8; ++j){
    int c = tid + 256 * j;
    yn[b * 2048 + c] = vals[j] * scale * norm_w[c];
  }
}

// ---------------- out projection: wave per column ----------------
__global__ __launch_bounds__(64)
void k_outproj(const float* __restrict__ yn, const float* __restrict__ wot,
               float* __restrict__ o){
  int col = blockIdx.x;
  int l = threadIdx.x;
  float acc[8] = {0.f, 0.f, 0.f, 0.f, 0.f, 0.f, 0.f, 0.f};
  const float* wp = wot + (size_t)col * 2048;
  #pragma unroll 4
  for (int i = 0; i < 32; ++i){
    int k = i * 64 + l;
    float w = wp[k];
    #pragma unroll
    for (int b = 0; b < 8; ++b)
      acc[b] += yn[b * 2048 + k] * w;
  }
  #pragma unroll
  for (int b = 0; b < 8; ++b){
    float v = acc[b];
    for (int s = 32; s; s >>= 1) v += __shfl_down(v, s, 64);
    if (l == 0) o[b * 1024 + col] = v;
  }
}

// ---------------- head: wave per output column ----------------
__global__ __launch_bounds__(64)
void k_head(const float* __restrict__ o, const float* __restrict__ wht,
            const float* __restrict__ b_head, float* __restrict__ out){
  int j = blockIdx.x;
  int l = threadIdx.x;
  float acc[8] = {0.f, 0.f, 0.f, 0.f, 0.f, 0.f, 0.f, 0.f};
  const float* wp = wht + (size_t)j * 1024;
  #pragma unroll 4
  for (int i = 0; i < 16; ++i){
    int k = i * 64 + l;
    float w = wp[k];
    #pragma unroll
    for (int b = 0; b < 8; ++b)
      acc[b] += o[b * 1024 + k] * w;
  }
  #pragma unroll
  for (int b = 0; b < 8; ++b){
    float v = acc[b];
    for (int s = 32; s; s >>= 1) v += __shfl_down(v, s, 64);
    if (l == 0) out[b * 64 + j] = v + b_head[j];
  }
}

extern "C" void kernel_launch(void* const* d_in, const int* in_sizes, int n_in,
                              void* d_out, int out_size, void* d_ws, size_t ws_size,
                              hipStream_t stream){
  (void)in_sizes; (void)n_in; (void)out_size; (void)ws_size;
  const float* x       = (const float*)d_in[0];
  const float* w_proj  = (const float*)d_in[1];
  const float* b_proj  = (const float*)d_in[2];
  const float* w_in    = (const float*)d_in[3];
  const float* conv_w  = (const float*)d_in[4];
  const float* conv_b  = (const float*)d_in[5];
  const float* A_log   = (const float*)d_in[6];
  const float* dt_bias = (const float*)d_in[7];
  const float* Dp      = (const float*)d_in[8];
  const float* norm_w  = (const float*)d_in[9];
  const float* w_out   = (const float*)d_in[10];
  const float* w_head  = (const float*)d_in[11];
  const float* b_head  = (const float*)d_in[12];
  float* out = (float*)d_out;

  char* ws = (char*)d_ws;
  size_t off = 0;
  auto alloc = [&](size_t bytes)->char*{
    char* p = ws + off; off += (bytes + 255) & ~(size_t)255; return p;
  };
  ushort_t* xb    = (ushort_t*)alloc((size_t)M_ROWS * 64 * 2);
  ushort_t* w1t   = (ushort_t*)alloc((size_t)1024 * 64 * 2);
  ushort_t* w2t   = (ushort_t*)alloc((size_t)2304 * 1024 * 2);
  ushort_t* wdt   = (ushort_t*)alloc((size_t)32 * 2048 * 2);
  float*    wzT   = (float*)alloc((size_t)2048 * 1024 * 4);
  float*    wot   = (float*)alloc((size_t)1024 * 2048 * 4);
  float*    wht   = (float*)alloc((size_t)64 * 1024 * 4);
  ushort_t* u16   = (ushort_t*)alloc((size_t)M_ROWS * 1024 * 2);
  ushort_t* xbc   = (ushort_t*)alloc((size_t)M_ROWS * 2304 * 2);
  float*    dtr   = (float*)alloc((size_t)M_ROWS * 32 * 4);
  float*    bmat  = (float*)alloc((size_t)M_ROWS * 128 * 4);
  float*    clast = (float*)alloc((size_t)8 * 128 * 4);
  float*    g     = (float*)alloc((size_t)M_ROWS * 4);
  float*    cfw   = (float*)alloc((size_t)256 * 2048 * 4);
  float*    ypart = (float*)alloc((size_t)8 * 64 * 2048 * 4);
  ushort_t* xhl   = (ushort_t*)alloc((size_t)8 * 2048 * 2);
  float*    yfin  = (float*)alloc((size_t)8 * 2048 * 4);
  float*    zl    = (float*)alloc((size_t)8 * 2048 * 4);
  float*    yn    = (float*)alloc((size_t)8 * 2048 * 4);
  float*    ov    = (float*)alloc((size_t)8 * 1024 * 4);

  k_prep<<<6096, 256, 0, stream>>>(x, w_proj, w_in, w_out, w_head,
                                   xb, w1t, w2t, wdt, wzT, wot, wht);

  k_gemm_bf16<<<(1024 / 128) * (M_ROWS / 128), 256, 0, stream>>>(xb, w1t, b_proj, u16, 64, 1024, 1024 / 128);

  k_gemm256<<<(M_ROWS / 256) * (2304 / 256), 512, 0, stream>>>(u16, w2t, xbc, 2304, 2304 / 256);

  k_dtg<<<M_ROWS / 128, 256, 0, stream>>>(u16, wdt, dtr);

  dim3 gcb(32, 8);
  k_convbc<<<gcb, 256, 0, stream>>>(xbc, conv_w, conv_b, bmat, clast);

  k_gdot<<<M_ROWS / 8, 256, 0, stream>>>(bmat, clast, g);
  k_coeff<<<256, 256, 0, stream>>>(dtr, dt_bias, A_log, g, cfw);

  dim3 gy(8, 64);
  k_ysum2f<<<gy, 256, 0, stream>>>(cfw, xbc, conv_w, conv_b, ypart, xhl);
  k_ysum_r2<<<M_ROWS / 256, 256, 0, stream>>>(ypart, xhl, Dp, yfin);

  k_zlast<<<2048, 64, 0, stream>>>(u16, wzT, zl);
  k_norm<<<8, 256, 0, stream>>>(yfin, zl, norm_w, yn);
  k_outproj<<<1024, 64, 0, stream>>>(yn, wot, ov);
  k_head<<<64, 64, 0, stream>>>(ov, wht, b_head, out);
}